// Round 1
// baseline (1763.234 us; speedup 1.0000x reference)
//
#include <hip/hip_runtime.h>

// Problem constants
#define BATCH   32
#define CDIM    256
#define HWSZ    1024                 // H*W
#define NTOK    32768                // B*H*W
#define KEMB    8192
#define ZQ_SIZE (BATCH * CDIM * HWSZ) // 8388608

// GEMM tiling
#define BM   128     // token rows per block
#define BK   128     // codebook cols per tile
#define BD   32      // d-chunk staged in LDS
#define BSS  (BK + 4) // padded LDS stride for B (keeps float4 alignment, spreads banks)
#define KSPLIT 4
#define KPER  (KEMB / KSPLIT)

// ws layout (bytes):
//   eSq: [0,        32768)          8192 f32
//   pv : [32768,    557056)         KSPLIT*NTOK f32 partial min values
//   pi : [557056,   1081344)        KSPLIT*NTOK i32 partial min indices
//   idx: [1081344,  1212416)        NTOK i32 final indices
#define WS_ESQ 0
#define WS_PV  32768
#define WS_PI  557056
#define WS_IDX 1081344

__global__ void esq_kernel(const float* __restrict__ emb, float* __restrict__ eSq) {
    int k    = blockIdx.x * 4 + (threadIdx.x >> 6);
    int lane = threadIdx.x & 63;
    float4 v = *(const float4*)&emb[k * CDIM + lane * 4];
    float s  = v.x * v.x + v.y * v.y + v.z * v.z + v.w * v.w;
    #pragma unroll
    for (int off = 32; off; off >>= 1) s += __shfl_down(s, off);
    if (lane == 0) eSq[k] = s;
}

__global__ void dist_kernel(const float* __restrict__ z, const float* __restrict__ emb,
                            const float* __restrict__ eSq,
                            float* __restrict__ pv, int* __restrict__ pi) {
    __shared__ __align__(16) char smem[(BD * BM + BD * BSS) * 4];
    float (*As)[BM]  = (float (*)[BM])smem;
    float (*Bs)[BSS] = (float (*)[BSS])(smem + BD * BM * 4);

    const int t   = threadIdx.x;
    const int tx  = t & 15;
    const int ty  = t >> 4;
    const int rb  = blockIdx.x & 255;   // row-block
    const int q   = blockIdx.x >> 8;    // K quarter
    const int m0  = rb * BM;
    const int bb  = m0 >> 10;           // batch index of this row block
    const int hw0 = m0 & 1023;

    float minv[8];
    int   mini[8];
    #pragma unroll
    for (int i = 0; i < 8; ++i) { minv[i] = 3.4028235e38f; mini[i] = 0; }

    const int kbeg = q * KPER;
    for (int k0 = kbeg; k0 < kbeg + KPER; k0 += BK) {
        float acc[8][8];
        #pragma unroll
        for (int r = 0; r < 8; ++r)
            #pragma unroll
            for (int c = 0; c < 8; ++c) acc[r][c] = 0.f;

        for (int d0 = 0; d0 < CDIM; d0 += BD) {
            __syncthreads();  // protect LDS from previous iteration's readers
            // A tile: 128 tokens x 32 dims; BCHW layout => contiguous along m for fixed c
            #pragma unroll
            for (int i = 0; i < 4; ++i) {
                int u  = t + i * 256;
                int m4 = (u & 31) << 2;
                int cR = u >> 5;
                float4 v = *(const float4*)&z[(bb << 18) + ((d0 + cR) << 10) + hw0 + m4];
                *(float4*)&As[cR][m4] = v;
            }
            // B tile: 128 codes x 32 dims, transposed into LDS
            #pragma unroll
            for (int i = 0; i < 4; ++i) {
                int u  = t + i * 256;
                int kR = u >> 3;
                int c4 = (u & 7) << 2;
                float4 v = *(const float4*)&emb[(k0 + kR) * CDIM + d0 + c4];
                Bs[c4 + 0][kR] = v.x;
                Bs[c4 + 1][kR] = v.y;
                Bs[c4 + 2][kR] = v.z;
                Bs[c4 + 3][kR] = v.w;
            }
            __syncthreads();
            #pragma unroll
            for (int d = 0; d < BD; ++d) {
                float a[8], b[8];
                *(float4*)&a[0] = *(const float4*)&As[d][(ty << 2)];
                *(float4*)&a[4] = *(const float4*)&As[d][64 + (ty << 2)];
                *(float4*)&b[0] = *(const float4*)&Bs[d][(tx << 2)];
                *(float4*)&b[4] = *(const float4*)&Bs[d][64 + (tx << 2)];
                #pragma unroll
                for (int r = 0; r < 8; ++r)
                    #pragma unroll
                    for (int c = 0; c < 8; ++c)
                        acc[r][c] = fmaf(a[r], b[c], acc[r][c]);
            }
        }
        // epilogue for this k-tile: dist = ||e||^2 - 2 z.e (z^2 row-constant, dropped)
        #pragma unroll
        for (int c = 0; c < 8; ++c) {
            int kk = (c < 4) ? ((tx << 2) + c) : (64 + (tx << 2) + (c - 4));
            int kg = k0 + kk;
            float es = eSq[kg];
            #pragma unroll
            for (int r = 0; r < 8; ++r) {
                float v = fmaf(-2.f, acc[r][c], es);
                if (v < minv[r]) { minv[r] = v; mini[r] = kg; }  // strict <: first min wins
            }
        }
    }

    // cross-thread reduction over tx (16 threads share each row); reuse LDS
    __syncthreads();
    float (*redV)[16] = (float (*)[16])smem;
    int   (*redI)[16] = (int   (*)[16])(smem + BM * 16 * 4);
    #pragma unroll
    for (int r = 0; r < 8; ++r) {
        int row = (r < 4) ? ((ty << 2) + r) : (64 + (ty << 2) + (r - 4));
        redV[row][tx] = minv[r];
        redI[row][tx] = mini[r];
    }
    __syncthreads();
    if (t < BM) {
        float bv = redV[t][0];
        int   bi = redI[t][0];
        #pragma unroll
        for (int i = 1; i < 16; ++i) {
            float v = redV[t][i];
            int  ii = redI[t][i];
            if (v < bv || (v == bv && ii < bi)) { bv = v; bi = ii; }
        }
        int n = m0 + t;
        pv[q * NTOK + n] = bv;
        pi[q * NTOK + n] = bi;
    }
}

__global__ void merge_kernel(const float* __restrict__ pv, const int* __restrict__ pi,
                             int* __restrict__ idxOut, float* __restrict__ idxFOut) {
    int n = blockIdx.x * 256 + threadIdx.x;
    float bv = pv[n];
    int   bi = pi[n];
    #pragma unroll
    for (int q = 1; q < KSPLIT; ++q) {
        float v = pv[q * NTOK + n];
        int  ii = pi[q * NTOK + n];
        if (v < bv || (v == bv && ii < bi)) { bv = v; bi = ii; }
    }
    idxOut[n]  = bi;
    idxFOut[n] = (float)bi;  // indices output, harness reads the buffer as f32
}

__global__ void gather_kernel(const float* __restrict__ emb, const int* __restrict__ idx,
                              float* __restrict__ out) {
    int o  = blockIdx.x * 256 + threadIdx.x;   // BCHW flat
    int hw = o & 1023;
    int c  = (o >> 10) & 255;
    int b  = o >> 18;
    int n  = (b << 10) | hw;
    out[o] = emb[idx[n] * CDIM + c];
}

extern "C" void kernel_launch(void* const* d_in, const int* in_sizes, int n_in,
                              void* d_out, int out_size, void* d_ws, size_t ws_size,
                              hipStream_t stream) {
    const float* z   = (const float*)d_in[0];
    const float* emb = (const float*)d_in[1];
    float* out = (float*)d_out;
    char*  ws  = (char*)d_ws;

    float* eSq = (float*)(ws + WS_ESQ);
    float* pv  = (float*)(ws + WS_PV);
    int*   pi  = (int*)(ws + WS_PI);
    int*   idx = (int*)(ws + WS_IDX);

    esq_kernel<<<KEMB / 4, 256, 0, stream>>>(emb, eSq);
    dist_kernel<<<256 * KSPLIT, 256, 0, stream>>>(z, emb, eSq, pv, pi);
    merge_kernel<<<NTOK / 256, 256, 0, stream>>>(pv, pi, idx, out + ZQ_SIZE);
    gather_kernel<<<ZQ_SIZE / 256, 256, 0, stream>>>(emb, idx, out);
}

// Round 2
// 717.051 us; speedup vs baseline: 2.4590x; 2.4590x over previous
//
#include <hip/hip_runtime.h>

// Problem constants
#define BATCH   32
#define CDIM    256
#define HWSZ    1024                 // H*W
#define NTOK    32768                // B*H*W
#define KEMB    8192
#define ZQ_SIZE (BATCH * CDIM * HWSZ) // 8388608

typedef short bf16x8 __attribute__((ext_vector_type(8)));
typedef float floatx4 __attribute__((ext_vector_type(4)));

// ---------------------------------------------------------------------------
// Fast path (MFMA split-bf16) workspace layout
//   esq : 8192 f32
//   e_hi/e_lo : 8192*256 bf16 each
//   z_hi/z_lo : 32768*256 bf16 each (transposed to [token][d])
//   part: MSPLIT*NTOK float4 (v1, i1bits, v2, i2bits)
//   idx : NTOK i32
#define MSPLIT   4
#define WS2_ESQ  0ULL
#define WS2_EH   32768ULL
#define WS2_EL   4227072ULL
#define WS2_ZH   8421376ULL
#define WS2_ZL   25198592ULL
#define WS2_PART 41975808ULL
#define WS2_IDX  44072960ULL
#define WS2_TOTAL 44204032ULL

// GEMM tiling (codes = M rows, tokens = N cols)
#define MB    256     // codes per block tile
#define NB    128     // tokens per block
#define MTPER (KEMB / MSPLIT / MB)   // 8 M-tiles per block
#define LSTR  80      // LDS row stride bytes (64B data + 16B pad)

// ---------------------------------------------------------------------------
__global__ void esq_kernel(const float* __restrict__ emb, float* __restrict__ eSq) {
    int k    = blockIdx.x * 4 + (threadIdx.x >> 6);
    int lane = threadIdx.x & 63;
    float4 v = *(const float4*)&emb[k * CDIM + lane * 4];
    float s  = v.x * v.x + v.y * v.y + v.z * v.z + v.w * v.w;
    #pragma unroll
    for (int off = 32; off; off >>= 1) s += __shfl_down(s, off);
    if (lane == 0) eSq[k] = s;
}

__device__ __forceinline__ unsigned int packsplit(float f) {
    unsigned int u  = __float_as_uint(f);
    unsigned int hi = (u + 0x7fffu + ((u >> 16) & 1u)) >> 16;
    float rest      = f - __uint_as_float(hi << 16);
    unsigned int u2 = __float_as_uint(rest);
    unsigned int lo = (u2 + 0x7fffu + ((u2 >> 16) & 1u)) >> 16;
    return (hi << 16) | lo;
}

__global__ void split_e_kernel(const float* __restrict__ e,
                               unsigned short* __restrict__ eh,
                               unsigned short* __restrict__ el) {
    int i = (blockIdx.x * 256 + threadIdx.x) * 4;
    float4 v = *(const float4*)&e[i];
    unsigned int p0 = packsplit(v.x), p1 = packsplit(v.y);
    unsigned int p2 = packsplit(v.z), p3 = packsplit(v.w);
    ushort4 hi = make_ushort4(p0 >> 16, p1 >> 16, p2 >> 16, p3 >> 16);
    ushort4 lo = make_ushort4(p0 & 0xffff, p1 & 0xffff, p2 & 0xffff, p3 & 0xffff);
    *(ushort4*)&eh[i] = hi;
    *(ushort4*)&el[i] = lo;
}

// z [b][d][hw] f32 -> z_hi/z_lo [token][d] bf16 (LDS transpose, packed hi|lo)
__global__ void split_z_kernel(const float* __restrict__ z,
                               unsigned short* __restrict__ zh,
                               unsigned short* __restrict__ zl) {
    __shared__ unsigned int tile[64][65];
    int b  = blockIdx.x >> 6;
    int r  = blockIdx.x & 63;
    int dt = r >> 4, ht = r & 15;
    int t  = threadIdx.x;
    #pragma unroll
    for (int i = 0; i < 4; ++i) {
        int u  = t + 256 * i;
        int dr = u >> 4;
        int c4 = (u & 15) * 4;
        float4 v = *(const float4*)&z[(((b * 256 + dt * 64 + dr) << 10) + ht * 64 + c4)];
        tile[dr][c4 + 0] = packsplit(v.x);
        tile[dr][c4 + 1] = packsplit(v.y);
        tile[dr][c4 + 2] = packsplit(v.z);
        tile[dr][c4 + 3] = packsplit(v.w);
    }
    __syncthreads();
    #pragma unroll
    for (int i = 0; i < 2; ++i) {
        int u  = t + 256 * i;
        int tr = u & 63;
        int d8 = u >> 6;   // 0..7
        unsigned short hi8[8], lo8[8];
        #pragma unroll
        for (int j = 0; j < 8; ++j) {
            unsigned int p = tile[d8 * 8 + j][tr];
            hi8[j] = (unsigned short)(p >> 16);
            lo8[j] = (unsigned short)(p & 0xffff);
        }
        size_t off = (size_t)(b * 1024 + ht * 64 + tr) * 256 + dt * 64 + d8 * 8;
        *(uint4*)&zh[off] = *(uint4*)hi8;
        *(uint4*)&zl[off] = *(uint4*)lo8;
    }
}

// ---------------------------------------------------------------------------
// Distance + per-token top-2 via 3-split bf16 MFMA.
// codes = M (rows), tokens = N (cols). Wave tile 128x64, block 256x128.
__global__ __launch_bounds__(256, 2)
void dist2_kernel(const unsigned short* __restrict__ zhp,
                  const unsigned short* __restrict__ zlp,
                  const unsigned short* __restrict__ ehp,
                  const unsigned short* __restrict__ elp,
                  const float* __restrict__ eSq,
                  float4* __restrict__ part) {
    __shared__ __align__(16) char lds[62464];
    char* Ah = lds;            // 256*80
    char* Al = lds + 20480;
    char* Bh = lds + 40960;    // 128*80
    char* Bl = lds + 51200;
    float* esqb = (float*)(lds + 61440);  // 256 f32

    const int t    = threadIdx.x;
    const int lane = t & 63;
    const int wv   = t >> 6;
    const int wm   = wv >> 1, wn = wv & 1;
    const int l15  = lane & 15, quad = lane >> 4;

    const int nb = blockIdx.x & 255;
    const int q  = blockIdx.x >> 8;
    const int n0 = nb * NB;
    const int cstrip = q * (KEMB / MSPLIT);

    const char* ehB = (const char*)ehp;
    const char* elB = (const char*)elp;
    const char* zhB = (const char*)zhp;
    const char* zlB = (const char*)zlp;

    // staging offsets
    const unsigned int aG = (unsigned int)(cstrip + t) * 512;            // + mt*131072 + dc*64 + i*16
    const unsigned int aL = (unsigned int)t * LSTR;                      // + i*16
    const unsigned int bG = (unsigned int)(n0 + (t & 127)) * 512 + ((t >> 7) * 16); // + dc*64 + i*32
    const unsigned int bL = (unsigned int)(t & 127) * LSTR + ((t >> 7) * 16);       // + i*32

    // fragment read offsets
    unsigned int aF[8], bF[4];
    #pragma unroll
    for (int rf = 0; rf < 8; ++rf) aF[rf] = (unsigned int)(wm * 128 + rf * 16 + l15) * LSTR + quad * 16;
    #pragma unroll
    for (int cf = 0; cf < 4; ++cf) bF[cf] = (unsigned int)(wn * 64 + cf * 16 + l15) * LSTR + quad * 16;

    float v1[4], v2[4];
    int   i1[4], i2[4];
    #pragma unroll
    for (int cf = 0; cf < 4; ++cf) { v1[cf] = 3.4e38f; v2[cf] = 3.4e38f; i1[cf] = 0; i2[cf] = 0; }

    for (int mt = 0; mt < MTPER; ++mt) {
        const int cb = cstrip + mt * MB;
        __syncthreads();   // protect esqb from previous epilogue readers
        if (t < 64) *(float4*)&esqb[t * 4] = *(const float4*)&eSq[cb + t * 4];

        floatx4 acc[8][4];
        #pragma unroll
        for (int rf = 0; rf < 8; ++rf)
            #pragma unroll
            for (int cf = 0; cf < 4; ++cf) acc[rf][cf] = (floatx4){0.f, 0.f, 0.f, 0.f};

        for (int dc = 0; dc < 8; ++dc) {
            const unsigned int d2 = (unsigned int)dc * 64;
            __syncthreads();
            {   // stage A (codes) hi+lo: 256 rows x 32 d
                const unsigned int go = aG + (unsigned int)mt * (MB * 512) + d2;
                #pragma unroll
                for (int i = 0; i < 4; ++i) {
                    uint4 vh = *(const uint4*)(ehB + go + i * 16);
                    uint4 vl = *(const uint4*)(elB + go + i * 16);
                    *(uint4*)(Ah + aL + i * 16) = vh;
                    *(uint4*)(Al + aL + i * 16) = vl;
                }
                // stage B (tokens) hi+lo: 128 rows x 32 d
                const unsigned int go2 = bG + d2;
                #pragma unroll
                for (int i = 0; i < 2; ++i) {
                    uint4 vh = *(const uint4*)(zhB + go2 + i * 32);
                    uint4 vl = *(const uint4*)(zlB + go2 + i * 32);
                    *(uint4*)(Bh + bL + i * 32) = vh;
                    *(uint4*)(Bl + bL + i * 32) = vl;
                }
            }
            __syncthreads();
            // one K=32 MFMA step per d-chunk
            bf16x8 bh[4], bl4[4];
            #pragma unroll
            for (int cf = 0; cf < 4; ++cf) {
                bh[cf]  = *(const bf16x8*)(Bh + bF[cf]);
                bl4[cf] = *(const bf16x8*)(Bl + bF[cf]);
            }
            #pragma unroll
            for (int rf = 0; rf < 8; ++rf) {
                bf16x8 ah  = *(const bf16x8*)(Ah + aF[rf]);
                bf16x8 al8 = *(const bf16x8*)(Al + aF[rf]);
                #pragma unroll
                for (int cf = 0; cf < 4; ++cf) {
                    acc[rf][cf] = __builtin_amdgcn_mfma_f32_16x16x32_bf16(al8, bh[cf],  acc[rf][cf], 0, 0, 0);
                    acc[rf][cf] = __builtin_amdgcn_mfma_f32_16x16x32_bf16(ah,  bl4[cf], acc[rf][cf], 0, 0, 0);
                    acc[rf][cf] = __builtin_amdgcn_mfma_f32_16x16x32_bf16(ah,  bh[cf],  acc[rf][cf], 0, 0, 0);
                }
            }
        }
        // epilogue: d = esq - 2*cross ; per-lane top-2 per column
        #pragma unroll
        for (int rf = 0; rf < 8; ++rf) {
            floatx4 eq = *(const floatx4*)&esqb[wm * 128 + rf * 16 + quad * 4];
            const int kb = cb + wm * 128 + rf * 16 + quad * 4;
            #pragma unroll
            for (int cf = 0; cf < 4; ++cf) {
                #pragma unroll
                for (int r = 0; r < 4; ++r) {
                    float v = fmaf(-2.f, acc[rf][cf][r], eq[r]);
                    int   k = kb + r;
                    if (v < v2[cf]) {
                        if (v < v1[cf]) { v2[cf] = v1[cf]; i2[cf] = i1[cf]; v1[cf] = v; i1[cf] = k; }
                        else            { v2[cf] = v;      i2[cf] = k; }
                    }
                }
            }
        }
    }

    // merge across row-quads (lanes sharing a column): xor 16 then xor 32
    #pragma unroll
    for (int cf = 0; cf < 4; ++cf) {
        #pragma unroll
        for (int s = 0; s < 2; ++s) {
            int m = s ? 32 : 16;
            float ov1 = __shfl(v1[cf], lane ^ m, 64);
            int   oi1 = __shfl(i1[cf], lane ^ m, 64);
            float ov2 = __shfl(v2[cf], lane ^ m, 64);
            int   oi2 = __shfl(i2[cf], lane ^ m, 64);
            if (ov1 < v2[cf]) {
                if (ov1 < v1[cf]) { v2[cf] = v1[cf]; i2[cf] = i1[cf]; v1[cf] = ov1; i1[cf] = oi1; }
                else              { v2[cf] = ov1;    i2[cf] = oi1; }
            }
            if (ov2 < v2[cf]) {
                if (ov2 < v1[cf]) { v2[cf] = v1[cf]; i2[cf] = i1[cf]; v1[cf] = ov2; i1[cf] = oi2; }
                else              { v2[cf] = ov2;    i2[cf] = oi2; }
            }
        }
    }

    __syncthreads();   // done with staging LDS; reuse as reduction buffer
    float4* red = (float4*)lds;  // 256 entries
    if (quad == 0) {
        #pragma unroll
        for (int cf = 0; cf < 4; ++cf)
            red[wm * 128 + wn * 64 + cf * 16 + l15] =
                make_float4(v1[cf], __int_as_float(i1[cf]), v2[cf], __int_as_float(i2[cf]));
    }
    __syncthreads();
    if (t < 128) {
        float4 a = red[t], b = red[128 + t];
        float av1 = a.x, av2 = a.z; int ai1 = __float_as_int(a.y), ai2 = __float_as_int(a.w);
        float bv1 = b.x, bv2 = b.z; int bi1 = __float_as_int(b.y), bi2 = __float_as_int(b.w);
        if (bv1 < av2) { if (bv1 < av1) { av2 = av1; ai2 = ai1; av1 = bv1; ai1 = bi1; } else { av2 = bv1; ai2 = bi1; } }
        if (bv2 < av2) { if (bv2 < av1) { av2 = av1; ai2 = ai1; av1 = bv2; ai1 = bi2; } else { av2 = bv2; ai2 = bi2; } }
        part[q * NTOK + n0 + t] = make_float4(av1, __int_as_float(ai1), av2, __int_as_float(ai2));
    }
}

// ---------------------------------------------------------------------------
// Merge MSPLIT partial top-2s, rescore both candidates in exact fp32, decide.
__global__ void rescore_kernel(const float* __restrict__ z, const float* __restrict__ emb,
                               const float* __restrict__ eSq, const float4* __restrict__ part,
                               int* __restrict__ idx, float* __restrict__ idxF) {
    int n    = blockIdx.x * 4 + (threadIdx.x >> 6);
    int lane = threadIdx.x & 63;
    float4 p = part[n];
    float v1 = p.x, v2 = p.z;
    int   i1 = __float_as_int(p.y), i2 = __float_as_int(p.w);
    #pragma unroll
    for (int qq = 1; qq < MSPLIT; ++qq) {
        float4 b = part[qq * NTOK + n];
        float bv1 = b.x, bv2 = b.z;
        int   bi1 = __float_as_int(b.y), bi2 = __float_as_int(b.w);
        if (bv1 < v2) { if (bv1 < v1) { v2 = v1; i2 = i1; v1 = bv1; i1 = bi1; } else { v2 = bv1; i2 = bi1; } }
        if (bv2 < v2) { if (bv2 < v1) { v2 = v1; i2 = i1; v1 = bv2; i1 = bi2; } else { v2 = bv2; i2 = bi2; } }
    }
    int c1 = i1, c2 = i2;
    const float* zp = z + ((size_t)(n >> 10) << 18) + (n & 1023);
    float s1 = 0.f, s2 = 0.f;
    #pragma unroll
    for (int j = 0; j < 4; ++j) {
        int d = lane + 64 * j;
        float zv = zp[(size_t)d << 10];
        s1 = fmaf(zv, emb[c1 * CDIM + d], s1);
        s2 = fmaf(zv, emb[c2 * CDIM + d], s2);
    }
    #pragma unroll
    for (int off = 32; off; off >>= 1) { s1 += __shfl_down(s1, off); s2 += __shfl_down(s2, off); }
    if (lane == 0) {
        float d1 = eSq[c1] - 2.f * s1;
        float d2 = eSq[c2] - 2.f * s2;
        int best = (d2 < d1 || (d2 == d1 && c2 < c1)) ? c2 : c1;
        idx[n]  = best;
        idxF[n] = (float)best;
    }
}

__global__ void gather_kernel(const float* __restrict__ emb, const int* __restrict__ idx,
                              float* __restrict__ out) {
    int o  = blockIdx.x * 256 + threadIdx.x;   // BCHW flat
    int hw = o & 1023;
    int c  = (o >> 10) & 255;
    int b  = o >> 18;
    int n  = (b << 10) | hw;
    out[o] = emb[idx[n] * CDIM + c];
}

// ---------------------------------------------------------------------------
// Fallback: round-1 fp32 path (used only if ws is too small for fast path)
#define F_BM  128
#define F_BK  128
#define F_BD  32
#define F_BSS (F_BK + 4)
#define F_KSPLIT 4
#define F_KPER  (KEMB / F_KSPLIT)
#define FWS_ESQ 0
#define FWS_PV  32768
#define FWS_PI  557056
#define FWS_IDX 1081344

__global__ void dist_kernel(const float* __restrict__ z, const float* __restrict__ emb,
                            const float* __restrict__ eSq,
                            float* __restrict__ pv, int* __restrict__ pi) {
    __shared__ __align__(16) char smem[(F_BD * F_BM + F_BD * F_BSS) * 4];
    float (*As)[F_BM]  = (float (*)[F_BM])smem;
    float (*Bs)[F_BSS] = (float (*)[F_BSS])(smem + F_BD * F_BM * 4);
    const int t = threadIdx.x, tx = t & 15, ty = t >> 4;
    const int rb = blockIdx.x & 255, q = blockIdx.x >> 8;
    const int m0 = rb * F_BM, bb = m0 >> 10, hw0 = m0 & 1023;
    float minv[8]; int mini[8];
    #pragma unroll
    for (int i = 0; i < 8; ++i) { minv[i] = 3.4028235e38f; mini[i] = 0; }
    const int kbeg = q * F_KPER;
    for (int k0 = kbeg; k0 < kbeg + F_KPER; k0 += F_BK) {
        float acc[8][8];
        #pragma unroll
        for (int r = 0; r < 8; ++r)
            #pragma unroll
            for (int c = 0; c < 8; ++c) acc[r][c] = 0.f;
        for (int d0 = 0; d0 < CDIM; d0 += F_BD) {
            __syncthreads();
            #pragma unroll
            for (int i = 0; i < 4; ++i) {
                int u = t + i * 256; int m4 = (u & 31) << 2; int cR = u >> 5;
                float4 v = *(const float4*)&z[(bb << 18) + ((d0 + cR) << 10) + hw0 + m4];
                *(float4*)&As[cR][m4] = v;
            }
            #pragma unroll
            for (int i = 0; i < 4; ++i) {
                int u = t + i * 256; int kR = u >> 3; int c4 = (u & 7) << 2;
                float4 v = *(const float4*)&emb[(k0 + kR) * CDIM + d0 + c4];
                Bs[c4 + 0][kR] = v.x; Bs[c4 + 1][kR] = v.y;
                Bs[c4 + 2][kR] = v.z; Bs[c4 + 3][kR] = v.w;
            }
            __syncthreads();
            #pragma unroll
            for (int d = 0; d < F_BD; ++d) {
                float a[8], b[8];
                *(float4*)&a[0] = *(const float4*)&As[d][(ty << 2)];
                *(float4*)&a[4] = *(const float4*)&As[d][64 + (ty << 2)];
                *(float4*)&b[0] = *(const float4*)&Bs[d][(tx << 2)];
                *(float4*)&b[4] = *(const float4*)&Bs[d][64 + (tx << 2)];
                #pragma unroll
                for (int r = 0; r < 8; ++r)
                    #pragma unroll
                    for (int c = 0; c < 8; ++c) acc[r][c] = fmaf(a[r], b[c], acc[r][c]);
            }
        }
        #pragma unroll
        for (int c = 0; c < 8; ++c) {
            int kk = (c < 4) ? ((tx << 2) + c) : (64 + (tx << 2) + (c - 4));
            int kg = k0 + kk;
            float es = eSq[kg];
            #pragma unroll
            for (int r = 0; r < 8; ++r) {
                float v = fmaf(-2.f, acc[r][c], es);
                if (v < minv[r]) { minv[r] = v; mini[r] = kg; }
            }
        }
    }
    __syncthreads();
    float (*redV)[16] = (float (*)[16])smem;
    int   (*redI)[16] = (int   (*)[16])(smem + F_BM * 16 * 4);
    #pragma unroll
    for (int r = 0; r < 8; ++r) {
        int row = (r < 4) ? ((ty << 2) + r) : (64 + (ty << 2) + (r - 4));
        redV[row][tx] = minv[r]; redI[row][tx] = mini[r];
    }
    __syncthreads();
    if (t < F_BM) {
        float bv = redV[t][0]; int bi = redI[t][0];
        #pragma unroll
        for (int i = 1; i < 16; ++i) {
            float v = redV[t][i]; int ii = redI[t][i];
            if (v < bv || (v == bv && ii < bi)) { bv = v; bi = ii; }
        }
        int n = m0 + t;
        pv[q * NTOK + n] = bv; pi[q * NTOK + n] = bi;
    }
}

__global__ void merge_kernel(const float* __restrict__ pv, const int* __restrict__ pi,
                             int* __restrict__ idxOut, float* __restrict__ idxFOut) {
    int n = blockIdx.x * 256 + threadIdx.x;
    float bv = pv[n]; int bi = pi[n];
    #pragma unroll
    for (int q = 1; q < F_KSPLIT; ++q) {
        float v = pv[q * NTOK + n]; int ii = pi[q * NTOK + n];
        if (v < bv || (v == bv && ii < bi)) { bv = v; bi = ii; }
    }
    idxOut[n] = bi; idxFOut[n] = (float)bi;
}

// ---------------------------------------------------------------------------
extern "C" void kernel_launch(void* const* d_in, const int* in_sizes, int n_in,
                              void* d_out, int out_size, void* d_ws, size_t ws_size,
                              hipStream_t stream) {
    const float* z   = (const float*)d_in[0];
    const float* emb = (const float*)d_in[1];
    float* out = (float*)d_out;
    char*  ws  = (char*)d_ws;

    if (ws_size >= WS2_TOTAL) {
        float* eSq = (float*)(ws + WS2_ESQ);
        unsigned short* eh = (unsigned short*)(ws + WS2_EH);
        unsigned short* el = (unsigned short*)(ws + WS2_EL);
        unsigned short* zh = (unsigned short*)(ws + WS2_ZH);
        unsigned short* zl = (unsigned short*)(ws + WS2_ZL);
        float4* part = (float4*)(ws + WS2_PART);
        int*    idx  = (int*)(ws + WS2_IDX);

        esq_kernel   <<<KEMB / 4, 256, 0, stream>>>(emb, eSq);
        split_e_kernel<<<KEMB * CDIM / 1024, 256, 0, stream>>>(emb, eh, el);
        split_z_kernel<<<2048, 256, 0, stream>>>(z, zh, zl);
        dist2_kernel <<<256 * MSPLIT, 256, 0, stream>>>(zh, zl, eh, el, eSq, part);
        rescore_kernel<<<NTOK / 4, 256, 0, stream>>>(z, emb, eSq, part, idx, out + ZQ_SIZE);
        gather_kernel<<<ZQ_SIZE / 256, 256, 0, stream>>>(emb, idx, out);
    } else {
        float* eSq = (float*)(ws + FWS_ESQ);
        float* pv  = (float*)(ws + FWS_PV);
        int*   pi  = (int*)(ws + FWS_PI);
        int*   idx = (int*)(ws + FWS_IDX);
        esq_kernel  <<<KEMB / 4, 256, 0, stream>>>(emb, eSq);
        dist_kernel <<<256 * F_KSPLIT, 256, 0, stream>>>(z, emb, eSq, pv, pi);
        merge_kernel<<<NTOK / 256, 256, 0, stream>>>(pv, pi, idx, out + ZQ_SIZE);
        gather_kernel<<<ZQ_SIZE / 256, 256, 0, stream>>>(emb, idx, out);
    }
}

// Round 3
// 554.097 us; speedup vs baseline: 3.1822x; 1.2941x over previous
//
#include <hip/hip_runtime.h>

// Problem constants
#define BATCH   32
#define CDIM    256
#define HWSZ    1024                 // H*W
#define NTOK    32768                // B*H*W
#define KEMB    8192
#define ZQ_SIZE (BATCH * CDIM * HWSZ) // 8388608

typedef short bf16x8 __attribute__((ext_vector_type(8)));
typedef float floatx4 __attribute__((ext_vector_type(4)));

// ---------------------------------------------------------------------------
// Fast path workspace layout (1-term bf16 MFMA + top-2/strip + exact rescore)
//   esq : 8192 f32
//   eh  : 8192*256 bf16
//   zh  : 32768*256 bf16 (transposed to [token][d])
//   part: MSPLIT*NTOK float4 (v1, i1bits, v2, i2bits)
//   idx : NTOK i32
#define MSPLIT   4
#define WS3_ESQ  0ULL
#define WS3_EH   32768ULL
#define WS3_ZH   4227072ULL
#define WS3_PART 21004288ULL
#define WS3_IDX  23101440ULL
#define WS3_TOTAL 23232512ULL

// GEMM tiling (codes = M rows, tokens = N cols)
#define MB    256     // codes per block M-tile
#define NB    128     // tokens per block
#define MTPER (KEMB / MSPLIT / MB)   // 8 M-tiles per block
#define LSTR  144     // LDS row stride bytes (128B data + 16B pad; 36 words)

__device__ __forceinline__ unsigned short bf16rne(float f) {
    unsigned int u = __float_as_uint(f);
    return (unsigned short)((u + 0x7fffu + ((u >> 16) & 1u)) >> 16);
}

// ---------------------------------------------------------------------------
// Fused ||e||^2 + bf16 convert of the codebook
__global__ void esqcvt_kernel(const float* __restrict__ emb, float* __restrict__ eSq,
                              unsigned short* __restrict__ eh) {
    int k    = blockIdx.x * 4 + (threadIdx.x >> 6);
    int lane = threadIdx.x & 63;
    float4 v = *(const float4*)&emb[k * CDIM + lane * 4];
    float s  = v.x * v.x + v.y * v.y + v.z * v.z + v.w * v.w;
    #pragma unroll
    for (int off = 32; off; off >>= 1) s += __shfl_down(s, off);
    ushort4 h = make_ushort4(bf16rne(v.x), bf16rne(v.y), bf16rne(v.z), bf16rne(v.w));
    *(ushort4*)&eh[k * CDIM + lane * 4] = h;
    if (lane == 0) eSq[k] = s;
}

// z [b][d][hw] f32 -> zh [token][d] bf16 (LDS transpose)
__global__ void splitz_kernel(const float* __restrict__ z, unsigned short* __restrict__ zh) {
    __shared__ unsigned int tile[64][65];
    int b  = blockIdx.x >> 6;
    int r  = blockIdx.x & 63;
    int dt = r >> 4, ht = r & 15;
    int t  = threadIdx.x;
    #pragma unroll
    for (int i = 0; i < 4; ++i) {
        int u  = t + 256 * i;
        int dr = u >> 4;
        int c4 = (u & 15) * 4;
        float4 v = *(const float4*)&z[(((size_t)(b * 256 + dt * 64 + dr)) << 10) + ht * 64 + c4];
        tile[dr][c4 + 0] = bf16rne(v.x);
        tile[dr][c4 + 1] = bf16rne(v.y);
        tile[dr][c4 + 2] = bf16rne(v.z);
        tile[dr][c4 + 3] = bf16rne(v.w);
    }
    __syncthreads();
    #pragma unroll
    for (int i = 0; i < 2; ++i) {
        int u  = t + 256 * i;
        int tr = u & 63;
        int d8 = u >> 6;   // 0..7
        unsigned short h8[8];
        #pragma unroll
        for (int j = 0; j < 8; ++j) h8[j] = (unsigned short)tile[d8 * 8 + j][tr];
        size_t off = (size_t)(b * 1024 + ht * 64 + tr) * 256 + dt * 64 + d8 * 8;
        *(uint4*)&zh[off] = *(uint4*)h8;
    }
}

// ---------------------------------------------------------------------------
// Approx distance + per-token/strip top-2 via single bf16 MFMA term.
// codes = M (rows), tokens = N (cols). Wave tile 128x64, block 256x128.
// LDS: Ah 256x144 = 36864, Bh 128x144 = 18432 -> 55296 B, 2 blocks/CU.
__global__ __launch_bounds__(256, 2)
void dist3_kernel(const unsigned short* __restrict__ zhp,
                  const unsigned short* __restrict__ ehp,
                  const float* __restrict__ eSq,
                  float4* __restrict__ part) {
    __shared__ __align__(16) char lds[55296];
    char* Ah = lds;            // 256 rows x 144 B (128 B data = 64 dims)
    char* Bh = lds + 36864;    // 128 rows x 144 B

    const int t    = threadIdx.x;
    const int lane = t & 63;
    const int wv   = t >> 6;
    const int wm   = wv >> 1, wn = wv & 1;
    const int l15  = lane & 15, quad = lane >> 4;

    const int nb = blockIdx.x & 255;
    const int q  = blockIdx.x >> 8;
    const int n0 = nb * NB;
    const int cstrip = q * (KEMB / MSPLIT);

    const char* ehB = (const char*)ehp;
    const char* zhB = (const char*)zhp;

    // staging: A thread t -> code row t (8x16B); B thread t -> token row t&127, half t>>7 (4x16B)
    const size_t   aGrow = (size_t)(cstrip + t) * 512;   // + mt*131072 + dr*128 + c*16
    const unsigned aLrow = (unsigned)t * LSTR;
    const int      rB    = t & 127, bh4 = (t >> 7) * 4;
    const size_t   bGrow = (size_t)(n0 + rB) * 512;      // + dr*128 + (bh4+i)*16
    const unsigned bLrow = (unsigned)rB * LSTR;

    // fragment offsets: row*144 + dk*64 + quad*16 (reads are 2-way bank-free at 36-word stride)
    unsigned rowA[8], rowB[4];
    #pragma unroll
    for (int rf = 0; rf < 8; ++rf) rowA[rf] = (unsigned)(wm * 128 + rf * 16 + l15) * LSTR;
    #pragma unroll
    for (int cf = 0; cf < 4; ++cf) rowB[cf] = 36864u + (unsigned)(wn * 64 + cf * 16 + l15) * LSTR;
    const unsigned qoff = (unsigned)quad * 16;

    float v1[4], v2[4];
    int   i1[4], i2[4];
    #pragma unroll
    for (int cf = 0; cf < 4; ++cf) { v1[cf] = 3.4e38f; v2[cf] = 3.4e38f; i1[cf] = 0; i2[cf] = 0; }

    for (int mt = 0; mt < MTPER; ++mt) {
        const int cb = cstrip + mt * MB;

        floatx4 acc[8][4];
        #pragma unroll
        for (int rf = 0; rf < 8; ++rf)
            #pragma unroll
            for (int cf = 0; cf < 4; ++cf) acc[rf][cf] = (floatx4){0.f, 0.f, 0.f, 0.f};

        for (int dr = 0; dr < 4; ++dr) {          // 64 dims per round
            __syncthreads();
            {   // stage A: 256 codes x 64 dims (hi only)
                const char* ag = ehB + aGrow + (size_t)mt * 131072 + dr * 128;
                #pragma unroll
                for (int c = 0; c < 8; ++c) {
                    uint4 v = *(const uint4*)(ag + c * 16);
                    *(uint4*)(Ah + aLrow + c * 16) = v;
                }
                // stage B: 128 tokens x 64 dims
                const char* bg = zhB + bGrow + dr * 128;
                #pragma unroll
                for (int i = 0; i < 4; ++i) {
                    uint4 v = *(const uint4*)(bg + (bh4 + i) * 16);
                    *(uint4*)(lds + bLrow + 36864u + (bh4 + i) * 16) = v;
                }
            }
            __syncthreads();
            #pragma unroll
            for (int dk = 0; dk < 2; ++dk) {
                const unsigned co = (unsigned)dk * 64 + qoff;
                bf16x8 bfr[4];
                #pragma unroll
                for (int cf = 0; cf < 4; ++cf) bfr[cf] = *(const bf16x8*)(lds + rowB[cf] + co);
                #pragma unroll
                for (int rf = 0; rf < 8; ++rf) {
                    bf16x8 a = *(const bf16x8*)(Ah + rowA[rf] + co);
                    #pragma unroll
                    for (int cf = 0; cf < 4; ++cf)
                        acc[rf][cf] = __builtin_amdgcn_mfma_f32_16x16x32_bf16(a, bfr[cf], acc[rf][cf], 0, 0, 0);
                }
            }
        }
        // epilogue: d = esq - 2*cross ; per-lane top-2 per column (eSq straight from L2, quad-broadcast)
        #pragma unroll
        for (int rf = 0; rf < 8; ++rf) {
            const int kb = cb + wm * 128 + rf * 16 + quad * 4;
            floatx4 eq = *(const floatx4*)&eSq[kb];
            #pragma unroll
            for (int cf = 0; cf < 4; ++cf) {
                #pragma unroll
                for (int r = 0; r < 4; ++r) {
                    float v = fmaf(-2.f, acc[rf][cf][r], eq[r]);
                    int   k = kb + r;
                    if (v < v2[cf]) {
                        if (v < v1[cf]) { v2[cf] = v1[cf]; i2[cf] = i1[cf]; v1[cf] = v; i1[cf] = k; }
                        else            { v2[cf] = v;      i2[cf] = k; }
                    }
                }
            }
        }
    }

    // merge across row-quads (lanes sharing a token column): xor 16 then xor 32
    #pragma unroll
    for (int cf = 0; cf < 4; ++cf) {
        #pragma unroll
        for (int s = 0; s < 2; ++s) {
            int m = s ? 32 : 16;
            float ov1 = __shfl(v1[cf], lane ^ m, 64);
            int   oi1 = __shfl(i1[cf], lane ^ m, 64);
            float ov2 = __shfl(v2[cf], lane ^ m, 64);
            int   oi2 = __shfl(i2[cf], lane ^ m, 64);
            if (ov1 < v2[cf]) {
                if (ov1 < v1[cf]) { v2[cf] = v1[cf]; i2[cf] = i1[cf]; v1[cf] = ov1; i1[cf] = oi1; }
                else              { v2[cf] = ov1;    i2[cf] = oi1; }
            }
            if (ov2 < v2[cf]) {
                if (ov2 < v1[cf]) { v2[cf] = v1[cf]; i2[cf] = i1[cf]; v1[cf] = ov2; i1[cf] = oi2; }
                else              { v2[cf] = ov2;    i2[cf] = oi2; }
            }
        }
    }

    __syncthreads();   // done with staging LDS; reuse as reduction buffer
    float4* red = (float4*)lds;  // 256 entries
    if (quad == 0) {
        #pragma unroll
        for (int cf = 0; cf < 4; ++cf)
            red[wm * 128 + wn * 64 + cf * 16 + l15] =
                make_float4(v1[cf], __int_as_float(i1[cf]), v2[cf], __int_as_float(i2[cf]));
    }
    __syncthreads();
    if (t < 128) {
        float4 a = red[t], b = red[128 + t];
        float av1 = a.x, av2 = a.z; int ai1 = __float_as_int(a.y), ai2 = __float_as_int(a.w);
        float bv1 = b.x, bv2 = b.z; int bi1 = __float_as_int(b.y), bi2 = __float_as_int(b.w);
        if (bv1 < av2) { if (bv1 < av1) { av2 = av1; ai2 = ai1; av1 = bv1; ai1 = bi1; } else { av2 = bv1; ai2 = bi1; } }
        if (bv2 < av2) { if (bv2 < av1) { av2 = av1; ai2 = ai1; av1 = bv2; ai1 = bi2; } else { av2 = bv2; ai2 = bi2; } }
        part[q * NTOK + n0 + t] = make_float4(av1, __int_as_float(ai1), av2, __int_as_float(ai2));
    }
}

// ---------------------------------------------------------------------------
// Rescore all 8 strip candidates (4 strips x top-2) in exact fp32, pick argmin
// with numpy tie-break (strict <, then lowest index). Strips are disjoint.
__global__ void rescore8_kernel(const float* __restrict__ z, const float* __restrict__ emb,
                                const float* __restrict__ eSq, const float4* __restrict__ part,
                                int* __restrict__ idx, float* __restrict__ idxF) {
    int n    = blockIdx.x * 4 + (threadIdx.x >> 6);
    int lane = threadIdx.x & 63;
    int c[8];
    #pragma unroll
    for (int s = 0; s < 4; ++s) {
        float4 p = part[s * NTOK + n];
        c[2 * s]     = __float_as_int(p.y);
        c[2 * s + 1] = __float_as_int(p.w);
    }
    const float* zp = z + ((size_t)(n >> 10) << 18) + (n & 1023);
    float acc[8];
    #pragma unroll
    for (int s = 0; s < 8; ++s) acc[s] = 0.f;
    #pragma unroll
    for (int j = 0; j < 4; ++j) {
        int d = lane + 64 * j;
        float zv = zp[(size_t)d << 10];
        #pragma unroll
        for (int s = 0; s < 8; ++s) acc[s] = fmaf(zv, emb[c[s] * CDIM + d], acc[s]);
    }
    #pragma unroll
    for (int off = 32; off; off >>= 1) {
        #pragma unroll
        for (int s = 0; s < 8; ++s) acc[s] += __shfl_down(acc[s], off);
    }
    if (lane == 0) {
        float bd = 3.4e38f; int bi = 0x7fffffff;
        #pragma unroll
        for (int s = 0; s < 8; ++s) {
            float dv = eSq[c[s]] - 2.f * acc[s];
            if (dv < bd || (dv == bd && c[s] < bi)) { bd = dv; bi = c[s]; }
        }
        idx[n]  = bi;
        idxF[n] = (float)bi;
    }
}

__global__ void gather_kernel(const float* __restrict__ emb, const int* __restrict__ idx,
                              float* __restrict__ out) {
    int o  = blockIdx.x * 256 + threadIdx.x;   // BCHW flat
    int hw = o & 1023;
    int c  = (o >> 10) & 255;
    int b  = o >> 18;
    int n  = (b << 10) | hw;
    out[o] = emb[idx[n] * CDIM + c];
}

// ---------------------------------------------------------------------------
// Fallback: round-1 fp32 path (used only if ws is too small for fast path)
#define F_BM  128
#define F_BK  128
#define F_BD  32
#define F_BSS (F_BK + 4)
#define F_KSPLIT 4
#define F_KPER  (KEMB / F_KSPLIT)
#define FWS_ESQ 0
#define FWS_PV  32768
#define FWS_PI  557056
#define FWS_IDX 1081344

__global__ void esq_kernel(const float* __restrict__ emb, float* __restrict__ eSq) {
    int k    = blockIdx.x * 4 + (threadIdx.x >> 6);
    int lane = threadIdx.x & 63;
    float4 v = *(const float4*)&emb[k * CDIM + lane * 4];
    float s  = v.x * v.x + v.y * v.y + v.z * v.z + v.w * v.w;
    #pragma unroll
    for (int off = 32; off; off >>= 1) s += __shfl_down(s, off);
    if (lane == 0) eSq[k] = s;
}

__global__ void dist_kernel(const float* __restrict__ z, const float* __restrict__ emb,
                            const float* __restrict__ eSq,
                            float* __restrict__ pv, int* __restrict__ pi) {
    __shared__ __align__(16) char smem[(F_BD * F_BM + F_BD * F_BSS) * 4];
    float (*As)[F_BM]  = (float (*)[F_BM])smem;
    float (*Bs)[F_BSS] = (float (*)[F_BSS])(smem + F_BD * F_BM * 4);
    const int t = threadIdx.x, tx = t & 15, ty = t >> 4;
    const int rb = blockIdx.x & 255, q = blockIdx.x >> 8;
    const int m0 = rb * F_BM, bb = m0 >> 10, hw0 = m0 & 1023;
    float minv[8]; int mini[8];
    #pragma unroll
    for (int i = 0; i < 8; ++i) { minv[i] = 3.4028235e38f; mini[i] = 0; }
    const int kbeg = q * F_KPER;
    for (int k0 = kbeg; k0 < kbeg + F_KPER; k0 += F_BK) {
        float acc[8][8];
        #pragma unroll
        for (int r = 0; r < 8; ++r)
            #pragma unroll
            for (int c = 0; c < 8; ++c) acc[r][c] = 0.f;
        for (int d0 = 0; d0 < CDIM; d0 += F_BD) {
            __syncthreads();
            #pragma unroll
            for (int i = 0; i < 4; ++i) {
                int u = t + i * 256; int m4 = (u & 31) << 2; int cR = u >> 5;
                float4 v = *(const float4*)&z[(bb << 18) + ((d0 + cR) << 10) + hw0 + m4];
                *(float4*)&As[cR][m4] = v;
            }
            #pragma unroll
            for (int i = 0; i < 4; ++i) {
                int u = t + i * 256; int kR = u >> 3; int c4 = (u & 7) << 2;
                float4 v = *(const float4*)&emb[(k0 + kR) * CDIM + d0 + c4];
                Bs[c4 + 0][kR] = v.x; Bs[c4 + 1][kR] = v.y;
                Bs[c4 + 2][kR] = v.z; Bs[c4 + 3][kR] = v.w;
            }
            __syncthreads();
            #pragma unroll
            for (int d = 0; d < F_BD; ++d) {
                float a[8], b[8];
                *(float4*)&a[0] = *(const float4*)&As[d][(ty << 2)];
                *(float4*)&a[4] = *(const float4*)&As[d][64 + (ty << 2)];
                *(float4*)&b[0] = *(const float4*)&Bs[d][(tx << 2)];
                *(float4*)&b[4] = *(const float4*)&Bs[d][64 + (tx << 2)];
                #pragma unroll
                for (int r = 0; r < 8; ++r)
                    #pragma unroll
                    for (int c = 0; c < 8; ++c) acc[r][c] = fmaf(a[r], b[c], acc[r][c]);
            }
        }
        #pragma unroll
        for (int c = 0; c < 8; ++c) {
            int kk = (c < 4) ? ((tx << 2) + c) : (64 + (tx << 2) + (c - 4));
            int kg = k0 + kk;
            float es = eSq[kg];
            #pragma unroll
            for (int r = 0; r < 8; ++r) {
                float v = fmaf(-2.f, acc[r][c], es);
                if (v < minv[r]) { minv[r] = v; mini[r] = kg; }
            }
        }
    }
    __syncthreads();
    float (*redV)[16] = (float (*)[16])smem;
    int   (*redI)[16] = (int   (*)[16])(smem + F_BM * 16 * 4);
    #pragma unroll
    for (int r = 0; r < 8; ++r) {
        int row = (r < 4) ? ((ty << 2) + r) : (64 + (ty << 2) + (r - 4));
        redV[row][tx] = minv[r]; redI[row][tx] = mini[r];
    }
    __syncthreads();
    if (t < F_BM) {
        float bv = redV[t][0]; int bi = redI[t][0];
        #pragma unroll
        for (int i = 1; i < 16; ++i) {
            float v = redV[t][i]; int ii = redI[t][i];
            if (v < bv || (v == bv && ii < bi)) { bv = v; bi = ii; }
        }
        int n = m0 + t;
        pv[q * NTOK + n] = bv; pi[q * NTOK + n] = bi;
    }
}

__global__ void merge_kernel(const float* __restrict__ pv, const int* __restrict__ pi,
                             int* __restrict__ idxOut, float* __restrict__ idxFOut) {
    int n = blockIdx.x * 256 + threadIdx.x;
    float bv = pv[n]; int bi = pi[n];
    #pragma unroll
    for (int q = 1; q < F_KSPLIT; ++q) {
        float v = pv[q * NTOK + n]; int ii = pi[q * NTOK + n];
        if (v < bv || (v == bv && ii < bi)) { bv = v; bi = ii; }
    }
    idxOut[n] = bi; idxFOut[n] = (float)bi;
}

// ---------------------------------------------------------------------------
extern "C" void kernel_launch(void* const* d_in, const int* in_sizes, int n_in,
                              void* d_out, int out_size, void* d_ws, size_t ws_size,
                              hipStream_t stream) {
    const float* z   = (const float*)d_in[0];
    const float* emb = (const float*)d_in[1];
    float* out = (float*)d_out;
    char*  ws  = (char*)d_ws;

    if (ws_size >= WS3_TOTAL) {
        float*          eSq  = (float*)(ws + WS3_ESQ);
        unsigned short* eh   = (unsigned short*)(ws + WS3_EH);
        unsigned short* zh   = (unsigned short*)(ws + WS3_ZH);
        float4*         part = (float4*)(ws + WS3_PART);
        int*            idx  = (int*)(ws + WS3_IDX);

        esqcvt_kernel<<<KEMB / 4, 256, 0, stream>>>(emb, eSq, eh);
        splitz_kernel<<<2048, 256, 0, stream>>>(z, zh);
        dist3_kernel <<<256 * MSPLIT, 256, 0, stream>>>(zh, eh, eSq, part);
        rescore8_kernel<<<NTOK / 4, 256, 0, stream>>>(z, emb, eSq, part, idx, out + ZQ_SIZE);
        gather_kernel<<<ZQ_SIZE / 256, 256, 0, stream>>>(emb, idx, out);
    } else {
        float* eSq = (float*)(ws + FWS_ESQ);
        float* pv  = (float*)(ws + FWS_PV);
        int*   pi  = (int*)(ws + FWS_PI);
        int*   idx = (int*)(ws + FWS_IDX);
        esq_kernel  <<<KEMB / 4, 256, 0, stream>>>(emb, eSq);
        dist_kernel <<<256 * F_KSPLIT, 256, 0, stream>>>(z, emb, eSq, pv, pi);
        merge_kernel<<<NTOK / 256, 256, 0, stream>>>(pv, pi, idx, out + ZQ_SIZE);
        gather_kernel<<<ZQ_SIZE / 256, 256, 0, stream>>>(emb, idx, out);
    }
}

// Round 5
// 448.620 us; speedup vs baseline: 3.9304x; 1.2351x over previous
//
#include <hip/hip_runtime.h>

// Problem constants
#define BATCH   32
#define CDIM    256
#define HWSZ    1024                 // H*W
#define NTOK    32768                // B*H*W
#define KEMB    8192
#define ZQ_SIZE (BATCH * CDIM * HWSZ) // 8388608

typedef short bf16x8 __attribute__((ext_vector_type(8)));
typedef float floatx4 __attribute__((ext_vector_type(4)));

#define MSPLIT 4                 // codebook strips
#define STRIP  (KEMB / MSPLIT)   // 2048 codes per strip
#define MB5    128               // codes per tile
#define NB5    128               // tokens per block
#define MT5    (STRIP / MB5)     // 16 tiles per strip

// ---------------------------------------------------------------------------
// Fast-path workspace layout
#define WS5_ESQ   0ULL           //  8192 f32 exact ||e||^2
#define WS5_EH    32768ULL       //  8192*256 bf16
#define WS5_ZH    4227072ULL     // 32768*256 bf16 ([token][d])
#define WS5_PART  21004288ULL    // MSPLIT*NTOK float4 (v1,i1,v2,i2)
#define WS5_IDX   23101440ULL    // NTOK i32
#define WS5_TOTAL 23232512ULL

__device__ __forceinline__ unsigned short bf16rne(float f) {
    unsigned int u = __float_as_uint(f);
    return (unsigned short)((u + 0x7fffu + ((u >> 16) & 1u)) >> 16);
}

#define GLOAD_LDS16(g, l) \
    __builtin_amdgcn_global_load_lds((const __attribute__((address_space(1))) void*)(g), \
                                     (__attribute__((address_space(3))) void*)(l), 16, 0, 0)

// ---------------------------------------------------------------------------
// Fused ||e||^2 + bf16 convert of the codebook
__global__ void esqcvt_kernel(const float* __restrict__ emb, float* __restrict__ eSq,
                              unsigned short* __restrict__ eh) {
    int k    = blockIdx.x * 4 + (threadIdx.x >> 6);
    int lane = threadIdx.x & 63;
    float4 v = *(const float4*)&emb[k * CDIM + lane * 4];
    float s  = v.x * v.x + v.y * v.y + v.z * v.z + v.w * v.w;
    #pragma unroll
    for (int off = 32; off; off >>= 1) s += __shfl_down(s, off);
    ushort4 h = make_ushort4(bf16rne(v.x), bf16rne(v.y), bf16rne(v.z), bf16rne(v.w));
    *(ushort4*)&eh[k * CDIM + lane * 4] = h;
    if (lane == 0) eSq[k] = s;
}

// z [b][d][hw] f32 -> zh [token][d] bf16 (LDS transpose)
__global__ void splitz_kernel(const float* __restrict__ z, unsigned short* __restrict__ zh) {
    __shared__ unsigned int tile[64][65];
    int b  = blockIdx.x >> 6;
    int r  = blockIdx.x & 63;
    int dt = r >> 4, ht = r & 15;
    int t  = threadIdx.x;
    #pragma unroll
    for (int i = 0; i < 4; ++i) {
        int u  = t + 256 * i;
        int dr = u >> 4;
        int c4 = (u & 15) * 4;
        float4 v = *(const float4*)&z[(((size_t)(b * 256 + dt * 64 + dr)) << 10) + ht * 64 + c4];
        tile[dr][c4 + 0] = bf16rne(v.x);
        tile[dr][c4 + 1] = bf16rne(v.y);
        tile[dr][c4 + 2] = bf16rne(v.z);
        tile[dr][c4 + 3] = bf16rne(v.w);
    }
    __syncthreads();
    #pragma unroll
    for (int i = 0; i < 2; ++i) {
        int u  = t + 256 * i;
        int tr = u & 63;
        int d8 = u >> 6;   // 0..7
        unsigned short h8[8];
        #pragma unroll
        for (int j = 0; j < 8; ++j) h8[j] = (unsigned short)tile[d8 * 8 + j][tr];
        size_t off = (size_t)(b * 1024 + ht * 64 + tr) * 256 + dt * 64 + d8 * 8;
        *(uint4*)&zh[off] = *(uint4*)h8;
    }
}

// ---------------------------------------------------------------------------
// dist5: bf16 MFMA distances, EXACT fp32 per-token/strip top-2 (round-3
// selection semantics). codes = M (rows), tokens = N (cols). Wave tile 64x64
// (2x2 wave grid), block tile 128x128. LDS 32KB: A 128x128B, B 128x128B,
// XOR chunk swizzle; staging via global_load_lds width=16.
__global__ __launch_bounds__(256, 3)
void dist5_kernel(const unsigned short* __restrict__ zhp,
                  const unsigned short* __restrict__ ehp,
                  const float* __restrict__ eSq,
                  float4* __restrict__ part) {
    __shared__ __align__(16) char lds[32768];

    const int t    = threadIdx.x;
    const int lane = t & 63;
    const int wv   = t >> 6;
    const int wm   = wv >> 1, wn = wv & 1;
    const int l15  = lane & 15, quad = lane >> 4;

    const int nb = blockIdx.x & 255;
    const int q  = blockIdx.x >> 8;
    const int n0 = nb * NB5;
    const int cstrip = q * STRIP;

    const char* ehB = (const char*)ehp;
    const char* zhB = (const char*)zhp;

    // DMA lane pattern: lane -> (row = lane>>3, slot = lane&7), logical chunk = slot ^ row
    const int dmaRow  = lane >> 3;
    const int dmaChnk = (lane & 7) ^ dmaRow;
    const unsigned laneGoff = (unsigned)dmaRow * 512 + (unsigned)dmaChnk * 16;

    // fragment LDS row bases (unswizzled part) + xor component
    unsigned aR[4], bR[4];
    #pragma unroll
    for (int rf = 0; rf < 4; ++rf) aR[rf] = (unsigned)(wm * 64 + rf * 16 + l15) * 128;
    #pragma unroll
    for (int cf = 0; cf < 4; ++cf) bR[cf] = 16384u + (unsigned)(wn * 64 + cf * 16 + l15) * 128;
    const unsigned cx = (unsigned)(l15 & 7);

    float v1[4], v2[4];
    int   i1[4], i2[4];
    #pragma unroll
    for (int cf = 0; cf < 4; ++cf) { v1[cf] = 3.4e38f; v2[cf] = 3.4e38f; i1[cf] = 0; i2[cf] = 0; }

    for (int mt = 0; mt < MT5; ++mt) {
        const int cb = cstrip + mt * MB5;

        floatx4 acc[4][4];
        #pragma unroll
        for (int rf = 0; rf < 4; ++rf)
            #pragma unroll
            for (int cf = 0; cf < 4; ++cf) acc[rf][cf] = (floatx4){0.f, 0.f, 0.f, 0.f};

        for (int dr = 0; dr < 4; ++dr) {
            __syncthreads();
            // A: 128 codes x 64 dims; 4 DMA per wave (8 rows x 8 chunks each)
            const char* ga = ehB + (size_t)(cb + wv * 32) * 512 + dr * 128 + laneGoff;
            char*       la = lds + (unsigned)(wv * 32) * 128;
            // B: 128 tokens x 64 dims
            const char* gb = zhB + (size_t)(n0 + wv * 32) * 512 + dr * 128 + laneGoff;
            char*       lb = lds + 16384u + (unsigned)(wv * 32) * 128;
            #pragma unroll
            for (int j = 0; j < 4; ++j) {
                GLOAD_LDS16(ga + j * 4096, la + j * 1024);
                GLOAD_LDS16(gb + j * 4096, lb + j * 1024);
            }
            __syncthreads();
            #pragma unroll
            for (int dk = 0; dk < 2; ++dk) {
                const unsigned xoff = (((unsigned)(dk * 4) + (unsigned)quad) ^ cx) * 16;
                bf16x8 bfr[4], afr[4];
                #pragma unroll
                for (int cf = 0; cf < 4; ++cf) bfr[cf] = *(const bf16x8*)(lds + bR[cf] + xoff);
                #pragma unroll
                for (int rf = 0; rf < 4; ++rf) afr[rf] = *(const bf16x8*)(lds + aR[rf] + xoff);
                #pragma unroll
                for (int rf = 0; rf < 4; ++rf)
                    #pragma unroll
                    for (int cf = 0; cf < 4; ++cf)
                        acc[rf][cf] = __builtin_amdgcn_mfma_f32_16x16x32_bf16(afr[rf], bfr[cf], acc[rf][cf], 0, 0, 0);
            }
        }

        // epilogue: d = esq - 2*cross ; exact fp32 per-lane top-2 per column
        #pragma unroll
        for (int rf = 0; rf < 4; ++rf) {
            const int kb = cb + wm * 64 + rf * 16 + quad * 4;
            floatx4 eq = *(const floatx4*)&eSq[kb];
            #pragma unroll
            for (int cf = 0; cf < 4; ++cf) {
                #pragma unroll
                for (int r = 0; r < 4; ++r) {
                    float v = fmaf(-2.f, acc[rf][cf][r], eq[r]);
                    int   k = kb + r;
                    if (v < v2[cf]) {
                        if (v < v1[cf]) { v2[cf] = v1[cf]; i2[cf] = i1[cf]; v1[cf] = v; i1[cf] = k; }
                        else            { v2[cf] = v;      i2[cf] = k; }
                    }
                }
            }
        }
    }

    // merge across row-quads (lanes sharing a token column): xor 16 then xor 32
    #pragma unroll
    for (int cf = 0; cf < 4; ++cf) {
        #pragma unroll
        for (int s = 0; s < 2; ++s) {
            int m = s ? 32 : 16;
            float ov1 = __shfl(v1[cf], lane ^ m, 64);
            int   oi1 = __shfl(i1[cf], lane ^ m, 64);
            float ov2 = __shfl(v2[cf], lane ^ m, 64);
            int   oi2 = __shfl(i2[cf], lane ^ m, 64);
            if (ov1 < v2[cf]) {
                if (ov1 < v1[cf]) { v2[cf] = v1[cf]; i2[cf] = i1[cf]; v1[cf] = ov1; i1[cf] = oi1; }
                else              { v2[cf] = ov1;    i2[cf] = oi1; }
            }
            if (ov2 < v2[cf]) {
                if (ov2 < v1[cf]) { v2[cf] = v1[cf]; i2[cf] = i1[cf]; v1[cf] = ov2; i1[cf] = oi2; }
                else              { v2[cf] = ov2;    i2[cf] = oi2; }
            }
        }
    }

    __syncthreads();   // staging LDS done; reuse as reduction buffer
    float4* red = (float4*)lds;  // 256 entries (wm x 128 tokens)
    if (quad == 0) {
        #pragma unroll
        for (int cf = 0; cf < 4; ++cf)
            red[wm * 128 + wn * 64 + cf * 16 + l15] =
                make_float4(v1[cf], __int_as_float(i1[cf]), v2[cf], __int_as_float(i2[cf]));
    }
    __syncthreads();
    if (t < 128) {
        float4 a = red[t], b = red[128 + t];
        float av1 = a.x, av2 = a.z; int ai1 = __float_as_int(a.y), ai2 = __float_as_int(a.w);
        float bv1 = b.x, bv2 = b.z; int bi1 = __float_as_int(b.y), bi2 = __float_as_int(b.w);
        if (bv1 < av2) { if (bv1 < av1) { av2 = av1; ai2 = ai1; av1 = bv1; ai1 = bi1; } else { av2 = bv1; ai2 = bi1; } }
        if (bv2 < av2) { if (bv2 < av1) { av2 = av1; ai2 = ai1; av1 = bv2; ai1 = bi2; } else { av2 = bv2; ai2 = bi2; } }
        part[q * NTOK + n0 + t] = make_float4(av1, __int_as_float(ai1), av2, __int_as_float(ai2));
    }
}

// ---------------------------------------------------------------------------
// Rescore all 8 strip candidates (4 strips x top-2) in exact fp32, pick argmin
// with numpy tie-break (strict <, then lowest index). Strips are disjoint.
__global__ void rescore8_kernel(const float* __restrict__ z, const float* __restrict__ emb,
                                const float* __restrict__ eSq, const float4* __restrict__ part,
                                int* __restrict__ idx, float* __restrict__ idxF) {
    int n    = blockIdx.x * 4 + (threadIdx.x >> 6);
    int lane = threadIdx.x & 63;
    int c[8];
    #pragma unroll
    for (int s = 0; s < 4; ++s) {
        float4 p = part[s * NTOK + n];
        c[2 * s]     = __float_as_int(p.y);
        c[2 * s + 1] = __float_as_int(p.w);
    }
    const float* zp = z + ((size_t)(n >> 10) << 18) + (n & 1023);
    float acc[8];
    #pragma unroll
    for (int s = 0; s < 8; ++s) acc[s] = 0.f;
    #pragma unroll
    for (int j = 0; j < 4; ++j) {
        int d = lane + 64 * j;
        float zv = zp[(size_t)d << 10];
        #pragma unroll
        for (int s = 0; s < 8; ++s) acc[s] = fmaf(zv, emb[c[s] * CDIM + d], acc[s]);
    }
    #pragma unroll
    for (int off = 32; off; off >>= 1) {
        #pragma unroll
        for (int s = 0; s < 8; ++s) acc[s] += __shfl_down(acc[s], off);
    }
    if (lane == 0) {
        float bd = 3.4e38f; int bi = 0x7fffffff;
        #pragma unroll
        for (int s = 0; s < 8; ++s) {
            float dv = eSq[c[s]] - 2.f * acc[s];
            if (dv < bd || (dv == bd && c[s] < bi)) { bd = dv; bi = c[s]; }
        }
        idx[n]  = bi;
        idxF[n] = (float)bi;
    }
}

// ---------------------------------------------------------------------------
// gather2: 32 tokens/block. Read each selected emb row once (coalesced 1KB),
// LDS-transpose, write out[b][c][hw] in 128B runs per channel.
__global__ void gather2_kernel(const float* __restrict__ emb, const int* __restrict__ idx,
                               float* __restrict__ out) {
    __shared__ float tile[32 * 260];
    __shared__ int rows[32];
    const int t  = threadIdx.x;
    const int n0 = blockIdx.x * 32;
    if (t < 32) rows[t] = idx[n0 + t];
    __syncthreads();
    {
        int r  = t >> 3;
        int c0 = (t & 7) * 32;
        const float* src = emb + (size_t)rows[r] * CDIM + c0;
        #pragma unroll
        for (int j = 0; j < 8; ++j) {
            float4 v = *(const float4*)(src + j * 4);
            *(float4*)&tile[r * 260 + c0 + j * 4] = v;
        }
    }
    __syncthreads();
    const int b   = n0 >> 10;
    const int hw0 = n0 & 1023;
    const int cg  = t >> 3;         // 0..31
    const int h4  = (t & 7) * 4;    // 0..28
    #pragma unroll
    for (int j = 0; j < 8; ++j) {
        int c = cg + j * 32;
        float4 v;
        v.x = tile[(h4 + 0) * 260 + c];
        v.y = tile[(h4 + 1) * 260 + c];
        v.z = tile[(h4 + 2) * 260 + c];
        v.w = tile[(h4 + 3) * 260 + c];
        *(float4*)&out[((size_t)b << 18) | ((size_t)c << 10) | (size_t)(hw0 + h4)] = v;
    }
}

// ---------------------------------------------------------------------------
// Fallback: round-1 fp32 path (used only if ws is too small for fast path)
#define F_BM  128
#define F_BK  128
#define F_BD  32
#define F_BSS (F_BK + 4)
#define F_KSPLIT 4
#define F_KPER  (KEMB / F_KSPLIT)
#define FWS_ESQ 0
#define FWS_PV  32768
#define FWS_PI  557056
#define FWS_IDX 1081344

__global__ void esq_kernel(const float* __restrict__ emb, float* __restrict__ eSq) {
    int k    = blockIdx.x * 4 + (threadIdx.x >> 6);
    int lane = threadIdx.x & 63;
    float4 v = *(const float4*)&emb[k * CDIM + lane * 4];
    float s  = v.x * v.x + v.y * v.y + v.z * v.z + v.w * v.w;
    #pragma unroll
    for (int off = 32; off; off >>= 1) s += __shfl_down(s, off);
    if (lane == 0) eSq[k] = s;
}

__global__ void dist_kernel(const float* __restrict__ z, const float* __restrict__ emb,
                            const float* __restrict__ eSq,
                            float* __restrict__ pv, int* __restrict__ pi) {
    __shared__ __align__(16) char smem[(F_BD * F_BM + F_BD * F_BSS) * 4];
    float (*As)[F_BM]  = (float (*)[F_BM])smem;
    float (*Bs)[F_BSS] = (float (*)[F_BSS])(smem + F_BD * F_BM * 4);
    const int t = threadIdx.x, tx = t & 15, ty = t >> 4;
    const int rb = blockIdx.x & 255, q = blockIdx.x >> 8;
    const int m0 = rb * F_BM, bb = m0 >> 10, hw0 = m0 & 1023;
    float minv[8]; int mini[8];
    #pragma unroll
    for (int i = 0; i < 8; ++i) { minv[i] = 3.4028235e38f; mini[i] = 0; }
    const int kbeg = q * F_KPER;
    for (int k0 = kbeg; k0 < kbeg + F_KPER; k0 += F_BK) {
        float acc[8][8];
        #pragma unroll
        for (int r = 0; r < 8; ++r)
            #pragma unroll
            for (int c = 0; c < 8; ++c) acc[r][c] = 0.f;
        for (int d0 = 0; d0 < CDIM; d0 += F_BD) {
            __syncthreads();
            #pragma unroll
            for (int i = 0; i < 4; ++i) {
                int u = t + i * 256; int m4 = (u & 31) << 2; int cR = u >> 5;
                float4 v = *(const float4*)&z[(bb << 18) + ((d0 + cR) << 10) + hw0 + m4];
                *(float4*)&As[cR][m4] = v;
            }
            #pragma unroll
            for (int i = 0; i < 4; ++i) {
                int u = t + i * 256; int kR = u >> 3; int c4 = (u & 7) << 2;
                float4 v = *(const float4*)&emb[(k0 + kR) * CDIM + d0 + c4];
                Bs[c4 + 0][kR] = v.x; Bs[c4 + 1][kR] = v.y;
                Bs[c4 + 2][kR] = v.z; Bs[c4 + 3][kR] = v.w;
            }
            __syncthreads();
            #pragma unroll
            for (int d = 0; d < F_BD; ++d) {
                float a[8], bb2[8];
                *(float4*)&a[0] = *(const float4*)&As[d][(ty << 2)];
                *(float4*)&a[4] = *(const float4*)&As[d][64 + (ty << 2)];
                *(float4*)&bb2[0] = *(const float4*)&Bs[d][(tx << 2)];
                *(float4*)&bb2[4] = *(const float4*)&Bs[d][64 + (tx << 2)];
                #pragma unroll
                for (int r = 0; r < 8; ++r)
                    #pragma unroll
                    for (int c = 0; c < 8; ++c) acc[r][c] = fmaf(a[r], bb2[c], acc[r][c]);
            }
        }
        #pragma unroll
        for (int c = 0; c < 8; ++c) {
            int kk = (c < 4) ? ((tx << 2) + c) : (64 + (tx << 2) + (c - 4));
            int kg = k0 + kk;
            float es = eSq[kg];
            #pragma unroll
            for (int r = 0; r < 8; ++r) {
                float v = fmaf(-2.f, acc[r][c], es);
                if (v < minv[r]) { minv[r] = v; mini[r] = kg; }
            }
        }
    }
    __syncthreads();
    float (*redV)[16] = (float (*)[16])smem;
    int   (*redI)[16] = (int   (*)[16])(smem + F_BM * 16 * 4);
    #pragma unroll
    for (int r = 0; r < 8; ++r) {
        int row = (r < 4) ? ((ty << 2) + r) : (64 + (ty << 2) + (r - 4));
        redV[row][tx] = minv[r]; redI[row][tx] = mini[r];
    }
    __syncthreads();
    if (t < F_BM) {
        float bv = redV[t][0]; int bi = redI[t][0];
        #pragma unroll
        for (int i = 1; i < 16; ++i) {
            float v = redV[t][i]; int ii = redI[t][i];
            if (v < bv || (v == bv && ii < bi)) { bv = v; bi = ii; }
        }
        int n = m0 + t;
        pv[q * NTOK + n] = bv; pi[q * NTOK + n] = bi;
    }
}

__global__ void merge_kernel(const float* __restrict__ pv, const int* __restrict__ pi,
                             int* __restrict__ idxOut, float* __restrict__ idxFOut) {
    int n = blockIdx.x * 256 + threadIdx.x;
    float bv = pv[n]; int bi = pi[n];
    #pragma unroll
    for (int q = 1; q < F_KSPLIT; ++q) {
        float v = pv[q * NTOK + n]; int ii = pi[q * NTOK + n];
        if (v < bv || (v == bv && ii < bi)) { bv = v; bi = ii; }
    }
    idxOut[n] = bi; idxFOut[n] = (float)bi;
}

// ---------------------------------------------------------------------------
extern "C" void kernel_launch(void* const* d_in, const int* in_sizes, int n_in,
                              void* d_out, int out_size, void* d_ws, size_t ws_size,
                              hipStream_t stream) {
    const float* z   = (const float*)d_in[0];
    const float* emb = (const float*)d_in[1];
    float* out = (float*)d_out;
    char*  ws  = (char*)d_ws;

    if (ws_size >= WS5_TOTAL) {
        float*          eSq  = (float*)(ws + WS5_ESQ);
        unsigned short* eh   = (unsigned short*)(ws + WS5_EH);
        unsigned short* zh   = (unsigned short*)(ws + WS5_ZH);
        float4*         part = (float4*)(ws + WS5_PART);
        int*            idx  = (int*)(ws + WS5_IDX);

        esqcvt_kernel <<<KEMB / 4, 256, 0, stream>>>(emb, eSq, eh);
        splitz_kernel <<<2048, 256, 0, stream>>>(z, zh);
        dist5_kernel  <<<256 * MSPLIT, 256, 0, stream>>>(zh, eh, eSq, part);
        rescore8_kernel<<<NTOK / 4, 256, 0, stream>>>(z, emb, eSq, part, idx, out + ZQ_SIZE);
        gather2_kernel<<<NTOK / 32, 256, 0, stream>>>(emb, idx, out);
    } else {
        float* eSq = (float*)(ws + FWS_ESQ);
        float* pv  = (float*)(ws + FWS_PV);
        int*   pi  = (int*)(ws + FWS_PI);
        int*   idx = (int*)(ws + FWS_IDX);
        esq_kernel  <<<KEMB / 4, 256, 0, stream>>>(emb, eSq);
        dist_kernel <<<256 * F_KSPLIT, 256, 0, stream>>>(z, emb, eSq, pv, pi);
        merge_kernel<<<NTOK / 256, 256, 0, stream>>>(pv, pi, idx, out + ZQ_SIZE);
        gather2_kernel<<<NTOK / 32, 256, 0, stream>>>(emb, idx, out);
    }
}

// Round 7
// 417.189 us; speedup vs baseline: 4.2265x; 1.0753x over previous
//
#include <hip/hip_runtime.h>

// Problem constants
#define BATCH   32
#define CDIM    256
#define HWSZ    1024                 // H*W
#define NTOK    32768                // B*H*W
#define KEMB    8192
#define ZQ_SIZE (BATCH * CDIM * HWSZ) // 8388608

typedef short bf16x8 __attribute__((ext_vector_type(8)));
typedef float floatx4 __attribute__((ext_vector_type(4)));

#define MSPLIT 4                 // codebook strips
#define STRIP  (KEMB / MSPLIT)   // 2048 codes per strip
#define MB7    128               // codes per tile
#define NB7    128               // tokens per block
#define MT7    (STRIP / MB7)     // 16 tiles per strip

// ---------------------------------------------------------------------------
// Fast-path workspace layout (identical to round 5)
#define WS7_ESQ   0ULL           //  8192 f32 exact ||e||^2
#define WS7_EH    32768ULL       //  8192*256 bf16
#define WS7_ZH    4227072ULL     // 32768*256 bf16 ([token][d])
#define WS7_PART  21004288ULL    // MSPLIT*NTOK float4 (v1,i1,v2,i2)
#define WS7_IDX   23101440ULL    // NTOK i32
#define WS7_TOTAL 23232512ULL

__device__ __forceinline__ unsigned short bf16rne(float f) {
    unsigned int u = __float_as_uint(f);
    return (unsigned short)((u + 0x7fffu + ((u >> 16) & 1u)) >> 16);
}

#define GLOAD_LDS16(g, l) \
    __builtin_amdgcn_global_load_lds((const __attribute__((address_space(1))) void*)(g), \
                                     (__attribute__((address_space(3))) void*)(l), 16, 0, 0)

// ---------------------------------------------------------------------------
// Fused ||e||^2 + bf16 convert of the codebook (round-5 verbatim)
__global__ void esqcvt_kernel(const float* __restrict__ emb, float* __restrict__ eSq,
                              unsigned short* __restrict__ eh) {
    int k    = blockIdx.x * 4 + (threadIdx.x >> 6);
    int lane = threadIdx.x & 63;
    float4 v = *(const float4*)&emb[k * CDIM + lane * 4];
    float s  = v.x * v.x + v.y * v.y + v.z * v.z + v.w * v.w;
    #pragma unroll
    for (int off = 32; off; off >>= 1) s += __shfl_down(s, off);
    ushort4 h = make_ushort4(bf16rne(v.x), bf16rne(v.y), bf16rne(v.z), bf16rne(v.w));
    *(ushort4*)&eh[k * CDIM + lane * 4] = h;
    if (lane == 0) eSq[k] = s;
}

// z [b][d][hw] f32 -> zh [token][d] bf16 (round-5 verbatim)
__global__ void splitz_kernel(const float* __restrict__ z, unsigned short* __restrict__ zh) {
    __shared__ unsigned int tile[64][65];
    int b  = blockIdx.x >> 6;
    int r  = blockIdx.x & 63;
    int dt = r >> 4, ht = r & 15;
    int t  = threadIdx.x;
    #pragma unroll
    for (int i = 0; i < 4; ++i) {
        int u  = t + 256 * i;
        int dr = u >> 4;
        int c4 = (u & 15) * 4;
        float4 v = *(const float4*)&z[(((size_t)(b * 256 + dt * 64 + dr)) << 10) + ht * 64 + c4];
        tile[dr][c4 + 0] = bf16rne(v.x);
        tile[dr][c4 + 1] = bf16rne(v.y);
        tile[dr][c4 + 2] = bf16rne(v.z);
        tile[dr][c4 + 3] = bf16rne(v.w);
    }
    __syncthreads();
    #pragma unroll
    for (int i = 0; i < 2; ++i) {
        int u  = t + 256 * i;
        int tr = u & 63;
        int d8 = u >> 6;   // 0..7
        unsigned short h8[8];
        #pragma unroll
        for (int j = 0; j < 8; ++j) h8[j] = (unsigned short)tile[d8 * 8 + j][tr];
        size_t off = (size_t)(b * 1024 + ht * 64 + tr) * 256 + dt * 64 + d8 * 8;
        *(uint4*)&zh[off] = *(uint4*)h8;
    }
}

// ---------------------------------------------------------------------------
// dist7: round-5 semantics (exact fp32 top-2, eSq, float4 part) with ONE
// change: double-buffered LDS (2 x 32KB), one barrier per 64-dim round,
// DMA prefetch of round r+1 overlapping the 32 MFMAs of round r.
__global__ __launch_bounds__(256, 2)
void dist7_kernel(const unsigned short* __restrict__ zhp,
                  const unsigned short* __restrict__ ehp,
                  const float* __restrict__ eSq,
                  float4* __restrict__ part) {
    __shared__ __align__(16) char lds[65536];

    const int t    = threadIdx.x;
    const int lane = t & 63;
    const int wv   = t >> 6;
    const int wm   = wv >> 1, wn = wv & 1;
    const int l15  = lane & 15, quad = lane >> 4;

    const int nb = blockIdx.x & 255;
    const int q  = blockIdx.x >> 8;
    const int n0 = nb * NB7;
    const int cstrip = q * STRIP;

    // DMA lane pattern: lane -> (row = lane>>3, slot = lane&7), global chunk = slot ^ row
    const int dmaRow  = lane >> 3;
    const int dmaChnk = (lane & 7) ^ dmaRow;
    const unsigned laneGoff = (unsigned)dmaRow * 512 + (unsigned)dmaChnk * 16;

    // wave-stationary global bases (A: codes, advances per tile; B: tokens, fixed)
    const char* gA0 = (const char*)ehp + (size_t)(cstrip + wv * 32) * 512 + laneGoff;
    const char* gB0 = (const char*)zhp + (size_t)(n0 + wv * 32) * 512 + laneGoff;
    const unsigned wvOff = (unsigned)wv * 4096;

    // fragment LDS row bases (within a 32KB buffer) + xor swizzle component
    unsigned aR[4], bR[4];
    #pragma unroll
    for (int rf = 0; rf < 4; ++rf) aR[rf] = (unsigned)(wm * 64 + rf * 16 + l15) * 128;
    #pragma unroll
    for (int cf = 0; cf < 4; ++cf) bR[cf] = 16384u + (unsigned)(wn * 64 + cf * 16 + l15) * 128;
    const unsigned cx = (unsigned)(l15 & 7);

    float v1[4], v2[4];
    int   i1[4], i2[4];
    #pragma unroll
    for (int cf = 0; cf < 4; ++cf) { v1[cf] = 3.4e38f; v2[cf] = 3.4e38f; i1[cf] = 0; i2[cf] = 0; }

    // pre-stage round 0 into buffer 0
    #pragma unroll
    for (int j = 0; j < 4; ++j) {
        GLOAD_LDS16(gA0 + j * 4096, lds + wvOff + j * 1024);
        GLOAD_LDS16(gB0 + j * 4096, lds + 16384u + wvOff + j * 1024);
    }

    int r = 0;
    for (int mt = 0; mt < MT7; ++mt) {
        floatx4 acc[4][4];
        #pragma unroll
        for (int rf = 0; rf < 4; ++rf)
            #pragma unroll
            for (int cf = 0; cf < 4; ++cf) acc[rf][cf] = (floatx4){0.f, 0.f, 0.f, 0.f};

        #pragma unroll
        for (int dr = 0; dr < 4; ++dr, ++r) {
            __syncthreads();   // drains DMA(r); also fences buf[(r+1)&1]'s previous readers
            if (r + 1 < 4 * MT7) {   // prefetch round r+1 into the other buffer
                const int rn  = r + 1;
                const int mtn = rn >> 2, drn = rn & 3;
                const unsigned bon = (unsigned)(rn & 1) << 15;
                const char* ga = gA0 + (size_t)mtn * 65536 + drn * 128;
                const char* gb = gB0 + drn * 128;
                #pragma unroll
                for (int j = 0; j < 4; ++j) {
                    GLOAD_LDS16(ga + j * 4096, lds + bon + wvOff + j * 1024);
                    GLOAD_LDS16(gb + j * 4096, lds + bon + 16384u + wvOff + j * 1024);
                }
            }
            const unsigned bo = (unsigned)(r & 1) << 15;
            #pragma unroll
            for (int dk = 0; dk < 2; ++dk) {
                const unsigned xoff = bo + (((unsigned)(dk * 4) + (unsigned)quad) ^ cx) * 16;
                bf16x8 bfr[4], afr[4];
                #pragma unroll
                for (int cf = 0; cf < 4; ++cf) bfr[cf] = *(const bf16x8*)(lds + bR[cf] + xoff);
                #pragma unroll
                for (int rf = 0; rf < 4; ++rf) afr[rf] = *(const bf16x8*)(lds + aR[rf] + xoff);
                #pragma unroll
                for (int rf = 0; rf < 4; ++rf)
                    #pragma unroll
                    for (int cf = 0; cf < 4; ++cf)
                        acc[rf][cf] = __builtin_amdgcn_mfma_f32_16x16x32_bf16(afr[rf], bfr[cf], acc[rf][cf], 0, 0, 0);
            }
        }

        // epilogue (round-5 verbatim): d = esq - 2*cross ; exact fp32 top-2
        #pragma unroll
        for (int rf = 0; rf < 4; ++rf) {
            const int kb = cstrip + mt * MB7 + wm * 64 + rf * 16 + quad * 4;
            floatx4 eq = *(const floatx4*)&eSq[kb];
            #pragma unroll
            for (int cf = 0; cf < 4; ++cf) {
                #pragma unroll
                for (int rr = 0; rr < 4; ++rr) {
                    float v = fmaf(-2.f, acc[rf][cf][rr], eq[rr]);
                    int   k = kb + rr;
                    if (v < v2[cf]) {
                        if (v < v1[cf]) { v2[cf] = v1[cf]; i2[cf] = i1[cf]; v1[cf] = v; i1[cf] = k; }
                        else            { v2[cf] = v;      i2[cf] = k; }
                    }
                }
            }
        }
    }

    // merge across row-quads (round-5 verbatim)
    #pragma unroll
    for (int cf = 0; cf < 4; ++cf) {
        #pragma unroll
        for (int s = 0; s < 2; ++s) {
            int m = s ? 32 : 16;
            float ov1 = __shfl(v1[cf], lane ^ m, 64);
            int   oi1 = __shfl(i1[cf], lane ^ m, 64);
            float ov2 = __shfl(v2[cf], lane ^ m, 64);
            int   oi2 = __shfl(i2[cf], lane ^ m, 64);
            if (ov1 < v2[cf]) {
                if (ov1 < v1[cf]) { v2[cf] = v1[cf]; i2[cf] = i1[cf]; v1[cf] = ov1; i1[cf] = oi1; }
                else              { v2[cf] = ov1;    i2[cf] = oi1; }
            }
            if (ov2 < v2[cf]) {
                if (ov2 < v1[cf]) { v2[cf] = v1[cf]; i2[cf] = i1[cf]; v1[cf] = ov2; i1[cf] = oi2; }
                else              { v2[cf] = ov2;    i2[cf] = oi2; }
            }
        }
    }

    __syncthreads();   // staging LDS done; reuse as reduction buffer
    float4* red = (float4*)lds;  // 256 entries
    if (quad == 0) {
        #pragma unroll
        for (int cf = 0; cf < 4; ++cf)
            red[wm * 128 + wn * 64 + cf * 16 + l15] =
                make_float4(v1[cf], __int_as_float(i1[cf]), v2[cf], __int_as_float(i2[cf]));
    }
    __syncthreads();
    if (t < 128) {
        float4 a = red[t], b = red[128 + t];
        float av1 = a.x, av2 = a.z; int ai1 = __float_as_int(a.y), ai2 = __float_as_int(a.w);
        float bv1 = b.x, bv2 = b.z; int bi1 = __float_as_int(b.y), bi2 = __float_as_int(b.w);
        if (bv1 < av2) { if (bv1 < av1) { av2 = av1; ai2 = ai1; av1 = bv1; ai1 = bi1; } else { av2 = bv1; ai2 = bi1; } }
        if (bv2 < av2) { if (bv2 < av1) { av2 = av1; ai2 = ai1; av1 = bv2; ai1 = bi2; } else { av2 = bv2; ai2 = bi2; } }
        part[q * NTOK + n0 + t] = make_float4(av1, __int_as_float(ai1), av2, __int_as_float(ai2));
    }
}

// ---------------------------------------------------------------------------
// Rescore (round-5 verbatim): 8 strip candidates, exact fp32, numpy tie-break.
__global__ void rescore8_kernel(const float* __restrict__ z, const float* __restrict__ emb,
                                const float* __restrict__ eSq, const float4* __restrict__ part,
                                int* __restrict__ idx, float* __restrict__ idxF) {
    int n    = blockIdx.x * 4 + (threadIdx.x >> 6);
    int lane = threadIdx.x & 63;
    int c[8];
    #pragma unroll
    for (int s = 0; s < 4; ++s) {
        float4 p = part[s * NTOK + n];
        c[2 * s]     = __float_as_int(p.y);
        c[2 * s + 1] = __float_as_int(p.w);
    }
    const float* zp = z + ((size_t)(n >> 10) << 18) + (n & 1023);
    float acc[8];
    #pragma unroll
    for (int s = 0; s < 8; ++s) acc[s] = 0.f;
    #pragma unroll
    for (int j = 0; j < 4; ++j) {
        int d = lane + 64 * j;
        float zv = zp[(size_t)d << 10];
        #pragma unroll
        for (int s = 0; s < 8; ++s) acc[s] = fmaf(zv, emb[c[s] * CDIM + d], acc[s]);
    }
    #pragma unroll
    for (int off = 32; off; off >>= 1) {
        #pragma unroll
        for (int s = 0; s < 8; ++s) acc[s] += __shfl_down(acc[s], off);
    }
    if (lane == 0) {
        float bd = 3.4e38f; int bi = 0x7fffffff;
        #pragma unroll
        for (int s = 0; s < 8; ++s) {
            float dv = eSq[c[s]] - 2.f * acc[s];
            if (dv < bd || (dv == bd && c[s] < bi)) { bd = dv; bi = c[s]; }
        }
        idx[n]  = bi;
        idxF[n] = (float)bi;
    }
}

// ---------------------------------------------------------------------------
// gather2 (unchanged): coalesced emb reads, LDS transpose, coalesced BCHW writes
__global__ void gather2_kernel(const float* __restrict__ emb, const int* __restrict__ idx,
                               float* __restrict__ out) {
    __shared__ float tile[32 * 260];
    __shared__ int rows[32];
    const int t  = threadIdx.x;
    const int n0 = blockIdx.x * 32;
    if (t < 32) rows[t] = idx[n0 + t];
    __syncthreads();
    {
        int r  = t >> 3;
        int c0 = (t & 7) * 32;
        const float* src = emb + (size_t)rows[r] * CDIM + c0;
        #pragma unroll
        for (int j = 0; j < 8; ++j) {
            float4 v = *(const float4*)(src + j * 4);
            *(float4*)&tile[r * 260 + c0 + j * 4] = v;
        }
    }
    __syncthreads();
    const int b   = n0 >> 10;
    const int hw0 = n0 & 1023;
    const int cg  = t >> 3;         // 0..31
    const int h4  = (t & 7) * 4;    // 0..28
    #pragma unroll
    for (int j = 0; j < 8; ++j) {
        int c = cg + j * 32;
        float4 v;
        v.x = tile[(h4 + 0) * 260 + c];
        v.y = tile[(h4 + 1) * 260 + c];
        v.z = tile[(h4 + 2) * 260 + c];
        v.w = tile[(h4 + 3) * 260 + c];
        *(float4*)&out[((size_t)b << 18) | ((size_t)c << 10) | (size_t)(hw0 + h4)] = v;
    }
}

// ---------------------------------------------------------------------------
// Fallback: round-1 fp32 path (used only if ws is too small for fast path)
#define F_BM  128
#define F_BK  128
#define F_BD  32
#define F_BSS (F_BK + 4)
#define F_KSPLIT 4
#define F_KPER  (KEMB / F_KSPLIT)
#define FWS_ESQ 0
#define FWS_PV  32768
#define FWS_PI  557056
#define FWS_IDX 1081344

__global__ void esq_kernel(const float* __restrict__ emb, float* __restrict__ eSq) {
    int k    = blockIdx.x * 4 + (threadIdx.x >> 6);
    int lane = threadIdx.x & 63;
    float4 v = *(const float4*)&emb[k * CDIM + lane * 4];
    float s  = v.x * v.x + v.y * v.y + v.z * v.z + v.w * v.w;
    #pragma unroll
    for (int off = 32; off; off >>= 1) s += __shfl_down(s, off);
    if (lane == 0) eSq[k] = s;
}

__global__ void dist_kernel(const float* __restrict__ z, const float* __restrict__ emb,
                            const float* __restrict__ eSq,
                            float* __restrict__ pv, int* __restrict__ pi) {
    __shared__ __align__(16) char smem[(F_BD * F_BM + F_BD * F_BSS) * 4];
    float (*As)[F_BM]  = (float (*)[F_BM])smem;
    float (*Bs)[F_BSS] = (float (*)[F_BSS])(smem + F_BD * F_BM * 4);
    const int t = threadIdx.x, tx = t & 15, ty = t >> 4;
    const int rb = blockIdx.x & 255, q = blockIdx.x >> 8;
    const int m0 = rb * F_BM, bb = m0 >> 10, hw0 = m0 & 1023;
    float minv[8]; int mini[8];
    #pragma unroll
    for (int i = 0; i < 8; ++i) { minv[i] = 3.4028235e38f; mini[i] = 0; }
    const int kbeg = q * F_KPER;
    for (int k0 = kbeg; k0 < kbeg + F_KPER; k0 += F_BK) {
        float acc[8][8];
        #pragma unroll
        for (int r = 0; r < 8; ++r)
            #pragma unroll
            for (int c = 0; c < 8; ++c) acc[r][c] = 0.f;
        for (int d0 = 0; d0 < CDIM; d0 += F_BD) {
            __syncthreads();
            #pragma unroll
            for (int i = 0; i < 4; ++i) {
                int u = t + i * 256; int m4 = (u & 31) << 2; int cR = u >> 5;
                float4 v = *(const float4*)&z[(bb << 18) + ((d0 + cR) << 10) + hw0 + m4];
                *(float4*)&As[cR][m4] = v;
            }
            #pragma unroll
            for (int i = 0; i < 4; ++i) {
                int u = t + i * 256; int kR = u >> 3; int c4 = (u & 7) << 2;
                float4 v = *(const float4*)&emb[(k0 + kR) * CDIM + d0 + c4];
                Bs[c4 + 0][kR] = v.x; Bs[c4 + 1][kR] = v.y;
                Bs[c4 + 2][kR] = v.z; Bs[c4 + 3][kR] = v.w;
            }
            __syncthreads();
            #pragma unroll
            for (int d = 0; d < F_BD; ++d) {
                float a[8], bb2[8];
                *(float4*)&a[0] = *(const float4*)&As[d][(ty << 2)];
                *(float4*)&a[4] = *(const float4*)&As[d][64 + (ty << 2)];
                *(float4*)&bb2[0] = *(const float4*)&Bs[d][(tx << 2)];
                *(float4*)&bb2[4] = *(const float4*)&Bs[d][64 + (tx << 2)];
                #pragma unroll
                for (int r = 0; r < 8; ++r)
                    #pragma unroll
                    for (int c = 0; c < 8; ++c) acc[r][c] = fmaf(a[r], bb2[c], acc[r][c]);
            }
        }
        #pragma unroll
        for (int c = 0; c < 8; ++c) {
            int kk = (c < 4) ? ((tx << 2) + c) : (64 + (tx << 2) + (c - 4));
            int kg = k0 + kk;
            float es = eSq[kg];
            #pragma unroll
            for (int r = 0; r < 8; ++r) {
                float v = fmaf(-2.f, acc[r][c], es);
                if (v < minv[r]) { minv[r] = v; mini[r] = kg; }
            }
        }
    }
    __syncthreads();
    float (*redV)[16] = (float (*)[16])smem;
    int   (*redI)[16] = (int   (*)[16])(smem + F_BM * 16 * 4);
    #pragma unroll
    for (int r = 0; r < 8; ++r) {
        int row = (r < 4) ? ((ty << 2) + r) : (64 + (ty << 2) + (r - 4));
        redV[row][tx] = minv[r]; redI[row][tx] = mini[r];
    }
    __syncthreads();
    if (t < F_BM) {
        float bv = redV[t][0]; int bi = redI[t][0];
        #pragma unroll
        for (int i = 1; i < 16; ++i) {
            float v = redV[t][i]; int ii = redI[t][i];
            if (v < bv || (v == bv && ii < bi)) { bv = v; bi = ii; }
        }
        int n = m0 + t;
        pv[q * NTOK + n] = bv; pi[q * NTOK + n] = bi;
    }
}

__global__ void merge_kernel(const float* __restrict__ pv, const int* __restrict__ pi,
                             int* __restrict__ idxOut, float* __restrict__ idxFOut) {
    int n = blockIdx.x * 256 + threadIdx.x;
    float bv = pv[n]; int bi = pi[n];
    #pragma unroll
    for (int q = 1; q < F_KSPLIT; ++q) {
        float v = pv[q * NTOK + n]; int ii = pi[q * NTOK + n];
        if (v < bv || (v == bv && ii < bi)) { bv = v; bi = ii; }
    }
    idxOut[n] = bi; idxFOut[n] = (float)bi;
}

// ---------------------------------------------------------------------------
extern "C" void kernel_launch(void* const* d_in, const int* in_sizes, int n_in,
                              void* d_out, int out_size, void* d_ws, size_t ws_size,
                              hipStream_t stream) {
    const float* z   = (const float*)d_in[0];
    const float* emb = (const float*)d_in[1];
    float* out = (float*)d_out;
    char*  ws  = (char*)d_ws;

    if (ws_size >= WS7_TOTAL) {
        float*          eSq  = (float*)(ws + WS7_ESQ);
        unsigned short* eh   = (unsigned short*)(ws + WS7_EH);
        unsigned short* zh   = (unsigned short*)(ws + WS7_ZH);
        float4*         part = (float4*)(ws + WS7_PART);
        int*            idx  = (int*)(ws + WS7_IDX);

        esqcvt_kernel <<<KEMB / 4, 256, 0, stream>>>(emb, eSq, eh);
        splitz_kernel <<<2048, 256, 0, stream>>>(z, zh);
        dist7_kernel  <<<256 * MSPLIT, 256, 0, stream>>>(zh, eh, eSq, part);
        rescore8_kernel<<<NTOK / 4, 256, 0, stream>>>(z, emb, eSq, part, idx, out + ZQ_SIZE);
        gather2_kernel<<<NTOK / 32, 256, 0, stream>>>(emb, idx, out);
    } else {
        float* eSq = (float*)(ws + FWS_ESQ);
        float* pv  = (float*)(ws + FWS_PV);
        int*   pi  = (int*)(ws + FWS_PI);
        int*   idx = (int*)(ws + FWS_IDX);
        esq_kernel  <<<KEMB / 4, 256, 0, stream>>>(emb, eSq);
        dist_kernel <<<256 * F_KSPLIT, 256, 0, stream>>>(z, emb, eSq, pv, pi);
        merge_kernel<<<NTOK / 256, 256, 0, stream>>>(pv, pi, idx, out + ZQ_SIZE);
        gather2_kernel<<<NTOK / 32, 256, 0, stream>>>(emb, idx, out);
    }
}

// Round 8
// 289.858 us; speedup vs baseline: 6.0831x; 1.4393x over previous
//
#include <hip/hip_runtime.h>

// Problem constants
#define BATCH   32
#define CDIM    256
#define HWSZ    1024                 // H*W
#define NTOK    32768                // B*H*W
#define KEMB    8192
#define ZQ_SIZE (BATCH * CDIM * HWSZ) // 8388608

typedef short bf16x8 __attribute__((ext_vector_type(8)));
typedef float floatx4 __attribute__((ext_vector_type(4)));

#define MSPLIT 4                 // codebook strips
#define STRIP  (KEMB / MSPLIT)   // 2048 codes per strip (11-bit local index)
#define MB8    128               // codes per tile
#define NB8    128               // tokens per block
#define MT8    (STRIP / MB8)     // 16 tiles per strip

// ---------------------------------------------------------------------------
// Fast-path workspace layout (bytes)
#define WS8_ESQ   0ULL           //  8192 f32 exact ||e||^2
#define WS8_EQM   32768ULL       //  8192 f32 ||e||^2*2048 + 2^23 (key bias)
#define WS8_EH    65536ULL       //  8192*256 bf16
#define WS8_ZH    4259840ULL     // 32768*256 bf16 hi ([token][d])
#define WS8_ZL    21037056ULL    // 32768*256 bf16 lo ([token][d])
#define WS8_PART  37814272ULL    // MSPLIT*NTOK uint4 (k1,k2,k3,0)
#define WS8_IDX   39911424ULL    // NTOK i32
#define WS8_TOTAL 40042496ULL

__device__ __forceinline__ unsigned short bf16rne(float f) {
    unsigned int u = __float_as_uint(f);
    return (unsigned short)((u + 0x7fffu + ((u >> 16) & 1u)) >> 16);
}
__device__ __forceinline__ unsigned int packsplit(float f) {
    unsigned int u  = __float_as_uint(f);
    unsigned int hi = (u + 0x7fffu + ((u >> 16) & 1u)) >> 16;
    float rest      = f - __uint_as_float(hi << 16);
    unsigned int u2 = __float_as_uint(rest);
    unsigned int lo = (u2 + 0x7fffu + ((u2 >> 16) & 1u)) >> 16;
    return (hi << 16) | lo;
}
__device__ __forceinline__ unsigned umin32(unsigned a, unsigned b) { return a < b ? a : b; }
__device__ __forceinline__ unsigned umax32(unsigned a, unsigned b) { return a > b ? a : b; }

#define GLOAD_LDS16(g, l) \
    __builtin_amdgcn_global_load_lds((const __attribute__((address_space(1))) void*)(g), \
                                     (__attribute__((address_space(3))) void*)(l), 16, 0, 0)

// ---------------------------------------------------------------------------
// Fused ||e||^2 (exact + key-biased) + bf16 convert of the codebook
__global__ void esqcvt_kernel(const float* __restrict__ emb, float* __restrict__ eSq,
                              float* __restrict__ eqm, unsigned short* __restrict__ eh) {
    int k    = blockIdx.x * 4 + (threadIdx.x >> 6);
    int lane = threadIdx.x & 63;
    float4 v = *(const float4*)&emb[k * CDIM + lane * 4];
    float s  = v.x * v.x + v.y * v.y + v.z * v.z + v.w * v.w;
    #pragma unroll
    for (int off = 32; off; off >>= 1) s += __shfl_down(s, off);
    ushort4 h = make_ushort4(bf16rne(v.x), bf16rne(v.y), bf16rne(v.z), bf16rne(v.w));
    *(ushort4*)&eh[k * CDIM + lane * 4] = h;
    if (lane == 0) { eSq[k] = s; eqm[k] = s * 2048.0f + 8388608.0f; }
}

// z [b][d][hw] f32 -> zh/zl [token][d] bf16 hi/lo (LDS transpose)
__global__ void splitz_kernel(const float* __restrict__ z, unsigned short* __restrict__ zh,
                              unsigned short* __restrict__ zl) {
    __shared__ unsigned int tile[64][65];
    int b  = blockIdx.x >> 6;
    int r  = blockIdx.x & 63;
    int dt = r >> 4, ht = r & 15;
    int t  = threadIdx.x;
    #pragma unroll
    for (int i = 0; i < 4; ++i) {
        int u  = t + 256 * i;
        int dr = u >> 4;
        int c4 = (u & 15) * 4;
        float4 v = *(const float4*)&z[(((size_t)(b * 256 + dt * 64 + dr)) << 10) + ht * 64 + c4];
        tile[dr][c4 + 0] = packsplit(v.x);
        tile[dr][c4 + 1] = packsplit(v.y);
        tile[dr][c4 + 2] = packsplit(v.z);
        tile[dr][c4 + 3] = packsplit(v.w);
    }
    __syncthreads();
    #pragma unroll
    for (int i = 0; i < 2; ++i) {
        int u  = t + 256 * i;
        int tr = u & 63;
        int d8 = u >> 6;   // 0..7
        unsigned short h8[8], l8[8];
        #pragma unroll
        for (int j = 0; j < 8; ++j) {
            unsigned int p = tile[d8 * 8 + j][tr];
            h8[j] = (unsigned short)(p >> 16);
            l8[j] = (unsigned short)(p & 0xffff);
        }
        size_t off = (size_t)(b * 1024 + ht * 64 + tr) * 256 + dt * 64 + d8 * 8;
        *(uint4*)&zh[off] = *(uint4*)h8;
        *(uint4*)&zl[off] = *(uint4*)l8;
    }
}

// ---------------------------------------------------------------------------
// dist8: round-7 double-buffered MFMA pipeline; per-token/strip TOP-3 as
// packed order-preserving integer keys.
//   key_f = esq*2048 - 4096*acc + 2^23  (one binade [2^23,2^24), ulp=1,
//           mantissa = 2048*d' < 2^21); key = (bits(key_f)<<11) | local_idx.
//   Granularity 2^-11 in distance units (~5e-4 with rounding); top-3/strip +
//   exact rescore makes a selection flip require THREE same-strip inversions.
__global__ __launch_bounds__(256, 2)
void dist8_kernel(const unsigned short* __restrict__ zhp,
                  const unsigned short* __restrict__ ehp,
                  const float* __restrict__ eqm,
                  uint4* __restrict__ part) {
    __shared__ __align__(16) char lds[65536];

    const int t    = threadIdx.x;
    const int lane = t & 63;
    const int wv   = t >> 6;
    const int wm   = wv >> 1, wn = wv & 1;
    const int l15  = lane & 15, quad = lane >> 4;

    const int nb = blockIdx.x & 255;
    const int q  = blockIdx.x >> 8;
    const int n0 = nb * NB8;
    const int cstrip = q * STRIP;

    // DMA lane pattern: lane -> (row = lane>>3, slot = lane&7), global chunk = slot ^ row
    const int dmaRow  = lane >> 3;
    const int dmaChnk = (lane & 7) ^ dmaRow;
    const unsigned laneGoff = (unsigned)dmaRow * 512 + (unsigned)dmaChnk * 16;

    const char* gA0 = (const char*)ehp + (size_t)(cstrip + wv * 32) * 512 + laneGoff;
    const char* gB0 = (const char*)zhp + (size_t)(n0 + wv * 32) * 512 + laneGoff;
    const unsigned wvOff = (unsigned)wv * 4096;

    // fragment LDS row bases (within a 32KB buffer) + xor swizzle component
    unsigned aR[4], bR[4];
    #pragma unroll
    for (int rf = 0; rf < 4; ++rf) aR[rf] = (unsigned)(wm * 64 + rf * 16 + l15) * 128;
    #pragma unroll
    for (int cf = 0; cf < 4; ++cf) bR[cf] = 16384u + (unsigned)(wn * 64 + cf * 16 + l15) * 128;
    const unsigned cx = (unsigned)(l15 & 7);

    unsigned k1[4], k2[4], k3[4];
    #pragma unroll
    for (int cf = 0; cf < 4; ++cf) { k1[cf] = 0xFFFFFFFFu; k2[cf] = 0xFFFFFFFFu; k3[cf] = 0xFFFFFFFFu; }

    // pre-stage round 0 into buffer 0
    #pragma unroll
    for (int j = 0; j < 4; ++j) {
        GLOAD_LDS16(gA0 + j * 4096, lds + wvOff + j * 1024);
        GLOAD_LDS16(gB0 + j * 4096, lds + 16384u + wvOff + j * 1024);
    }

    int r = 0;
    for (int mt = 0; mt < MT8; ++mt) {
        floatx4 acc[4][4];
        #pragma unroll
        for (int rf = 0; rf < 4; ++rf)
            #pragma unroll
            for (int cf = 0; cf < 4; ++cf) acc[rf][cf] = (floatx4){0.f, 0.f, 0.f, 0.f};

        #pragma unroll
        for (int dr = 0; dr < 4; ++dr, ++r) {
            __syncthreads();   // drains DMA(r); fences buf[(r+1)&1]'s previous readers
            if (r + 1 < 4 * MT8) {   // prefetch round r+1 into the other buffer
                const int rn  = r + 1;
                const int mtn = rn >> 2, drn = rn & 3;
                const unsigned bon = (unsigned)(rn & 1) << 15;
                const char* ga = gA0 + (size_t)mtn * 65536 + drn * 128;
                const char* gb = gB0 + drn * 128;
                #pragma unroll
                for (int j = 0; j < 4; ++j) {
                    GLOAD_LDS16(ga + j * 4096, lds + bon + wvOff + j * 1024);
                    GLOAD_LDS16(gb + j * 4096, lds + bon + 16384u + wvOff + j * 1024);
                }
            }
            const unsigned bo = (unsigned)(r & 1) << 15;
            #pragma unroll
            for (int dk = 0; dk < 2; ++dk) {
                const unsigned xoff = bo + (((unsigned)(dk * 4) + (unsigned)quad) ^ cx) * 16;
                bf16x8 bfr[4], afr[4];
                #pragma unroll
                for (int cf = 0; cf < 4; ++cf) bfr[cf] = *(const bf16x8*)(lds + bR[cf] + xoff);
                #pragma unroll
                for (int rf = 0; rf < 4; ++rf) afr[rf] = *(const bf16x8*)(lds + aR[rf] + xoff);
                #pragma unroll
                for (int rf = 0; rf < 4; ++rf)
                    #pragma unroll
                    for (int cf = 0; cf < 4; ++cf)
                        acc[rf][cf] = __builtin_amdgcn_mfma_f32_16x16x32_bf16(afr[rf], bfr[cf], acc[rf][cf], 0, 0, 0);
            }
        }

        // epilogue: branch-free top-3 insert of packed keys
        #pragma unroll
        for (int rf = 0; rf < 4; ++rf) {
            const int kb = cstrip + mt * MB8 + wm * 64 + rf * 16 + quad * 4;
            floatx4 eq = *(const floatx4*)&eqm[kb];
            const unsigned lb = (unsigned)(mt * MB8 + wm * 64 + rf * 16 + quad * 4);
            #pragma unroll
            for (int cf = 0; cf < 4; ++cf) {
                #pragma unroll
                for (int rr = 0; rr < 4; ++rr) {
                    float kf = fmaf(acc[rf][cf][rr], -4096.f, eq[rr]);
                    unsigned key = (__float_as_uint(kf) << 11) | (lb + (unsigned)rr);
                    unsigned m1 = umax32(k1[cf], key);
                    k1[cf] = umin32(k1[cf], key);
                    unsigned m2 = umax32(k2[cf], m1);
                    k2[cf] = umin32(k2[cf], m1);
                    k3[cf] = umin32(k3[cf], m2);
                }
            }
        }
    }

    // merge across row-quads (lanes sharing a token column): xor 16 then xor 32
    #pragma unroll
    for (int cf = 0; cf < 4; ++cf) {
        #pragma unroll
        for (int s = 0; s < 2; ++s) {
            int m = s ? 32 : 16;
            unsigned o1 = (unsigned)__shfl((int)k1[cf], lane ^ m, 64);
            unsigned o2 = (unsigned)__shfl((int)k2[cf], lane ^ m, 64);
            unsigned o3 = (unsigned)__shfl((int)k3[cf], lane ^ m, 64);
            unsigned a1  = umax32(k1[cf], o1);
            k1[cf]       = umin32(k1[cf], o1);
            unsigned b1  = umin32(k2[cf], o2);
            unsigned r3a = umax32(a1, b1);
            k2[cf]       = umin32(a1, b1);
            k3[cf]       = umin32(r3a, umin32(k3[cf], o3));
        }
    }

    __syncthreads();   // staging LDS done; reuse as reduction buffer
    uint4* red = (uint4*)lds;  // 256 entries (wm x 128 tokens)
    if (quad == 0) {
        #pragma unroll
        for (int cf = 0; cf < 4; ++cf)
            red[wm * 128 + wn * 64 + cf * 16 + l15] = make_uint4(k1[cf], k2[cf], k3[cf], 0u);
    }
    __syncthreads();
    if (t < 128) {
        uint4 a = red[t], b = red[128 + t];
        unsigned a1  = umax32(a.x, b.x);
        unsigned r1  = umin32(a.x, b.x);
        unsigned b1  = umin32(a.y, b.y);
        unsigned r3a = umax32(a1, b1);
        unsigned r2  = umin32(a1, b1);
        unsigned r3  = umin32(r3a, umin32(a.z, b.z));
        part[q * NTOK + n0 + t] = make_uint4(r1, r2, r3, 0u);
    }
}

// ---------------------------------------------------------------------------
// Rescore 12 strip candidates (4 strips x top-3) with near-exact fp32
// (z = hi+lo bf16 pair, error <= 2^-18 |z|); numpy tie-break.
__global__ void rescore12_kernel(const unsigned short* __restrict__ zh,
                                 const unsigned short* __restrict__ zl,
                                 const float* __restrict__ emb,
                                 const float* __restrict__ eSq, const uint4* __restrict__ part,
                                 int* __restrict__ idx, float* __restrict__ idxF) {
    int n    = blockIdx.x * 4 + (threadIdx.x >> 6);
    int lane = threadIdx.x & 63;
    int c[12];
    #pragma unroll
    for (int s = 0; s < 4; ++s) {
        uint4 p = part[s * NTOK + n];
        c[3 * s]     = s * STRIP + (int)(p.x & 0x7FFu);
        c[3 * s + 1] = s * STRIP + (int)(p.y & 0x7FFu);
        c[3 * s + 2] = s * STRIP + (int)(p.z & 0x7FFu);
    }
    // reconstruct 4 contiguous dims of z for this lane (hi+lo pair)
    ushort4 h = *(const ushort4*)&zh[(size_t)n * CDIM + lane * 4];
    ushort4 l = *(const ushort4*)&zl[(size_t)n * CDIM + lane * 4];
    float z0 = __uint_as_float((unsigned)h.x << 16) + __uint_as_float((unsigned)l.x << 16);
    float z1 = __uint_as_float((unsigned)h.y << 16) + __uint_as_float((unsigned)l.y << 16);
    float z2 = __uint_as_float((unsigned)h.z << 16) + __uint_as_float((unsigned)l.z << 16);
    float z3 = __uint_as_float((unsigned)h.w << 16) + __uint_as_float((unsigned)l.w << 16);
    float acc[12];
    #pragma unroll
    for (int s = 0; s < 12; ++s) {
        float4 e = *(const float4*)&emb[(size_t)c[s] * CDIM + lane * 4];
        acc[s] = fmaf(z0, e.x, fmaf(z1, e.y, fmaf(z2, e.z, z3 * e.w)));
    }
    #pragma unroll
    for (int off = 32; off; off >>= 1) {
        #pragma unroll
        for (int s = 0; s < 12; ++s) acc[s] += __shfl_down(acc[s], off);
    }
    if (lane == 0) {
        float bd = 3.4e38f; int bi = 0x7fffffff;
        #pragma unroll
        for (int s = 0; s < 12; ++s) {
            float dv = eSq[c[s]] - 2.f * acc[s];
            if (dv < bd || (dv == bd && c[s] < bi)) { bd = dv; bi = c[s]; }
        }
        idx[n]  = bi;
        idxF[n] = (float)bi;
    }
}

// ---------------------------------------------------------------------------
// gather2: coalesced emb reads, LDS transpose, coalesced BCHW writes
__global__ void gather2_kernel(const float* __restrict__ emb, const int* __restrict__ idx,
                               float* __restrict__ out) {
    __shared__ float tile[32 * 260];
    __shared__ int rows[32];
    const int t  = threadIdx.x;
    const int n0 = blockIdx.x * 32;
    if (t < 32) rows[t] = idx[n0 + t];
    __syncthreads();
    {
        int r  = t >> 3;
        int c0 = (t & 7) * 32;
        const float* src = emb + (size_t)rows[r] * CDIM + c0;
        #pragma unroll
        for (int j = 0; j < 8; ++j) {
            float4 v = *(const float4*)(src + j * 4);
            *(float4*)&tile[r * 260 + c0 + j * 4] = v;
        }
    }
    __syncthreads();
    const int b   = n0 >> 10;
    const int hw0 = n0 & 1023;
    const int cg  = t >> 3;         // 0..31
    const int h4  = (t & 7) * 4;    // 0..28
    #pragma unroll
    for (int j = 0; j < 8; ++j) {
        int c = cg + j * 32;
        float4 v;
        v.x = tile[(h4 + 0) * 260 + c];
        v.y = tile[(h4 + 1) * 260 + c];
        v.z = tile[(h4 + 2) * 260 + c];
        v.w = tile[(h4 + 3) * 260 + c];
        *(float4*)&out[((size_t)b << 18) | ((size_t)c << 10) | (size_t)(hw0 + h4)] = v;
    }
}

// ---------------------------------------------------------------------------
// Fallback: round-1 fp32 path (used only if ws is too small for fast path)
#define F_BM  128
#define F_BK  128
#define F_BD  32
#define F_BSS (F_BK + 4)
#define F_KSPLIT 4
#define F_KPER  (KEMB / F_KSPLIT)
#define FWS_ESQ 0
#define FWS_PV  32768
#define FWS_PI  557056
#define FWS_IDX 1081344

__global__ void esq_kernel(const float* __restrict__ emb, float* __restrict__ eSq) {
    int k    = blockIdx.x * 4 + (threadIdx.x >> 6);
    int lane = threadIdx.x & 63;
    float4 v = *(const float4*)&emb[k * CDIM + lane * 4];
    float s  = v.x * v.x + v.y * v.y + v.z * v.z + v.w * v.w;
    #pragma unroll
    for (int off = 32; off; off >>= 1) s += __shfl_down(s, off);
    if (lane == 0) eSq[k] = s;
}

__global__ void dist_kernel(const float* __restrict__ z, const float* __restrict__ emb,
                            const float* __restrict__ eSq,
                            float* __restrict__ pv, int* __restrict__ pi) {
    __shared__ __align__(16) char smem[(F_BD * F_BM + F_BD * F_BSS) * 4];
    float (*As)[F_BM]  = (float (*)[F_BM])smem;
    float (*Bs)[F_BSS] = (float (*)[F_BSS])(smem + F_BD * F_BM * 4);
    const int t = threadIdx.x, tx = t & 15, ty = t >> 4;
    const int rb = blockIdx.x & 255, q = blockIdx.x >> 8;
    const int m0 = rb * F_BM, bb = m0 >> 10, hw0 = m0 & 1023;
    float minv[8]; int mini[8];
    #pragma unroll
    for (int i = 0; i < 8; ++i) { minv[i] = 3.4028235e38f; mini[i] = 0; }
    const int kbeg = q * F_KPER;
    for (int k0 = kbeg; k0 < kbeg + F_KPER; k0 += F_BK) {
        float acc[8][8];
        #pragma unroll
        for (int r = 0; r < 8; ++r)
            #pragma unroll
            for (int c = 0; c < 8; ++c) acc[r][c] = 0.f;
        for (int d0 = 0; d0 < CDIM; d0 += F_BD) {
            __syncthreads();
            #pragma unroll
            for (int i = 0; i < 4; ++i) {
                int u = t + i * 256; int m4 = (u & 31) << 2; int cR = u >> 5;
                float4 v = *(const float4*)&z[(bb << 18) + ((d0 + cR) << 10) + hw0 + m4];
                *(float4*)&As[cR][m4] = v;
            }
            #pragma unroll
            for (int i = 0; i < 4; ++i) {
                int u = t + i * 256; int kR = u >> 3; int c4 = (u & 7) << 2;
                float4 v = *(const float4*)&emb[(k0 + kR) * CDIM + d0 + c4];
                Bs[c4 + 0][kR] = v.x; Bs[c4 + 1][kR] = v.y;
                Bs[c4 + 2][kR] = v.z; Bs[c4 + 3][kR] = v.w;
            }
            __syncthreads();
            #pragma unroll
            for (int d = 0; d < F_BD; ++d) {
                float a[8], bb2[8];
                *(float4*)&a[0] = *(const float4*)&As[d][(ty << 2)];
                *(float4*)&a[4] = *(const float4*)&As[d][64 + (ty << 2)];
                *(float4*)&bb2[0] = *(const float4*)&Bs[d][(tx << 2)];
                *(float4*)&bb2[4] = *(const float4*)&Bs[d][64 + (tx << 2)];
                #pragma unroll
                for (int r = 0; r < 8; ++r)
                    #pragma unroll
                    for (int c = 0; c < 8; ++c) acc[r][c] = fmaf(a[r], bb2[c], acc[r][c]);
            }
        }
        #pragma unroll
        for (int c = 0; c < 8; ++c) {
            int kk = (c < 4) ? ((tx << 2) + c) : (64 + (tx << 2) + (c - 4));
            int kg = k0 + kk;
            float es = eSq[kg];
            #pragma unroll
            for (int r = 0; r < 8; ++r) {
                float v = fmaf(-2.f, acc[r][c], es);
                if (v < minv[r]) { minv[r] = v; mini[r] = kg; }
            }
        }
    }
    __syncthreads();
    float (*redV)[16] = (float (*)[16])smem;
    int   (*redI)[16] = (int   (*)[16])(smem + F_BM * 16 * 4);
    #pragma unroll
    for (int r = 0; r < 8; ++r) {
        int row = (r < 4) ? ((ty << 2) + r) : (64 + (ty << 2) + (r - 4));
        redV[row][tx] = minv[r]; redI[row][tx] = mini[r];
    }
    __syncthreads();
    if (t < F_BM) {
        float bv = redV[t][0]; int bi = redI[t][0];
        #pragma unroll
        for (int i = 1; i < 16; ++i) {
            float v = redV[t][i]; int ii = redI[t][i];
            if (v < bv || (v == bv && ii < bi)) { bv = v; bi = ii; }
        }
        int n = m0 + t;
        pv[q * NTOK + n] = bv; pi[q * NTOK + n] = bi;
    }
}

__global__ void merge_kernel(const float* __restrict__ pv, const int* __restrict__ pi,
                             int* __restrict__ idxOut, float* __restrict__ idxFOut) {
    int n = blockIdx.x * 256 + threadIdx.x;
    float bv = pv[n]; int bi = pi[n];
    #pragma unroll
    for (int q = 1; q < F_KSPLIT; ++q) {
        float v = pv[q * NTOK + n]; int ii = pi[q * NTOK + n];
        if (v < bv || (v == bv && ii < bi)) { bv = v; bi = ii; }
    }
    idxOut[n] = bi; idxFOut[n] = (float)bi;
}

// ---------------------------------------------------------------------------
extern "C" void kernel_launch(void* const* d_in, const int* in_sizes, int n_in,
                              void* d_out, int out_size, void* d_ws, size_t ws_size,
                              hipStream_t stream) {
    const float* z   = (const float*)d_in[0];
    const float* emb = (const float*)d_in[1];
    float* out = (float*)d_out;
    char*  ws  = (char*)d_ws;

    if (ws_size >= WS8_TOTAL) {
        float*          eSq  = (float*)(ws + WS8_ESQ);
        float*          eqm  = (float*)(ws + WS8_EQM);
        unsigned short* eh   = (unsigned short*)(ws + WS8_EH);
        unsigned short* zh   = (unsigned short*)(ws + WS8_ZH);
        unsigned short* zl   = (unsigned short*)(ws + WS8_ZL);
        uint4*          part = (uint4*)(ws + WS8_PART);
        int*            idx  = (int*)(ws + WS8_IDX);

        esqcvt_kernel <<<KEMB / 4, 256, 0, stream>>>(emb, eSq, eqm, eh);
        splitz_kernel <<<2048, 256, 0, stream>>>(z, zh, zl);
        dist8_kernel  <<<256 * MSPLIT, 256, 0, stream>>>(zh, eh, eqm, part);
        rescore12_kernel<<<NTOK / 4, 256, 0, stream>>>(zh, zl, emb, eSq, part, idx, out + ZQ_SIZE);
        gather2_kernel<<<NTOK / 32, 256, 0, stream>>>(emb, idx, out);
    } else {
        float* eSq = (float*)(ws + FWS_ESQ);
        float* pv  = (float*)(ws + FWS_PV);
        int*   pi  = (int*)(ws + FWS_PI);
        int*   idx = (int*)(ws + FWS_IDX);
        esq_kernel  <<<KEMB / 4, 256, 0, stream>>>(emb, eSq);
        dist_kernel <<<256 * F_KSPLIT, 256, 0, stream>>>(z, emb, eSq, pv, pi);
        merge_kernel<<<NTOK / 256, 256, 0, stream>>>(pv, pi, idx, out + ZQ_SIZE);
        gather2_kernel<<<NTOK / 32, 256, 0, stream>>>(emb, idx, out);
    }
}